// Round 2
// baseline (2265.369 us; speedup 1.0000x reference)
//
#include <hip/hip_runtime.h>

typedef __bf16 bf16;
typedef __bf16 bf16x8 __attribute__((ext_vector_type(8)));
typedef float  f32x4  __attribute__((ext_vector_type(4)));

#define BM 128
#define BN 128
#define BKT 64
#define LDK (BKT + 8)
#define LDT 72   // gram LDS row stride (t-dim padded)

// AMODE: 0 = gather concat [obj[s] | pred | obj[o]] (f32 -> bf16)
//        1 = bn_lrelu(scale*x+shift) applied to bf16 source
//        2 = f32 source * invcnt[row]
//        3 = plain bf16 copy
//        4 = bf16 source with row permutation (row = perm[m0+r])
// EPI:   0 = store bf16 + column stats atomics
//        2 = bn_lrelu(out-col scale/shift) then scatter: cols<512 -> pooled[s] (atomic),
//            512..639 -> outF (new_p), >=640 -> pooled[o] (atomic)   [tier-3 fallback]
//        3 = store f32 + column stats atomics
//        4 = bn_lrelu(out-col scale/shift); cols<512 -> dense bf16 chunk buffer at
//            row-rbase (sorted rows -> later contiguous segmented pooling);
//            cols>=512 -> outF[perm[row]] (new_p)
template<int AMODE, int EPI>
__global__ __launch_bounds__(256) void gemm_k(
    const bf16* __restrict__ Abf, const float* __restrict__ Af32,
    const float* __restrict__ obj, const float* __restrict__ pred,
    const int* __restrict__ edges, const float* __restrict__ invcnt,
    const float* __restrict__ scale, const float* __restrict__ shift,   // input-col bn (AMODE==1)
    const float* __restrict__ oscale, const float* __restrict__ oshift, // output-col bn (EPI==2/4)
    const bf16* __restrict__ WT,      // (N,K) bf16, pre-transposed
    bf16* __restrict__ outB, float* __restrict__ outF,
    float* __restrict__ pooled, float* __restrict__ gsum, float* __restrict__ gsq,
    int M, int N, int K,
    const int* __restrict__ perm, int rbase)
{
  __shared__ __align__(16) bf16 As[BM][LDK];
  __shared__ __align__(16) bf16 Bs[BN][LDK];
  __shared__ float sc_sh[(AMODE == 1) ? 512 : 1];
  __shared__ float sh_sh[(AMODE == 1) ? 512 : 1];
  __shared__ float osc[(EPI == 2 || EPI == 4) ? BN : 1];
  __shared__ float osh[(EPI == 2 || EPI == 4) ? BN : 1];
  __shared__ int eS[(AMODE == 0 || EPI == 2 || EPI == 4) ? BM : 1];
  __shared__ int eO[(AMODE == 0 || EPI == 2) ? BM : 1];

  const int tid = threadIdx.x;
  const int m0 = rbase + blockIdx.y * BM;
  const int n0 = blockIdx.x * BN;
  const int lane = tid & 63;
  const int w = tid >> 6;
  const int wm = (w >> 1) * 64;
  const int wn = (w & 1) * 64;
  const int l15 = lane & 15;
  const int quad = lane >> 4;

  if (AMODE == 1) {
    for (int c = tid; c < K; c += 256) { sc_sh[c] = scale[c]; sh_sh[c] = shift[c]; }
  }
  if (EPI == 2 || EPI == 4) {
    if (tid < BN) { osc[tid] = oscale[n0 + tid]; osh[tid] = oshift[n0 + tid]; }
  }
  if (AMODE == 0 || EPI == 2) {
    if (tid < BM) {
      int r = m0 + tid; if (r >= M) r = M - 1;
      eS[tid] = edges[2 * r];
      eO[tid] = edges[2 * r + 1];
    }
  }
  if (EPI == 4) {
    if (tid < BM) {
      int r = m0 + tid; if (r >= M) r = M - 1;
      eS[tid] = perm[r];          // original triple index for this sorted row
    }
  }
  __syncthreads();

  f32x4 acc[4][4];
  #pragma unroll
  for (int i = 0; i < 4; ++i)
    #pragma unroll
    for (int j = 0; j < 4; ++j)
      acc[i][j] = (f32x4){0.f, 0.f, 0.f, 0.f};

  for (int k0 = 0; k0 < K; k0 += BKT) {
    // ---- stage B^T tile: 128 rows (cols of W) x 64 k
    {
      int idx = tid;
      #pragma unroll
      for (int it = 0; it < 4; ++it, idx += 256) {
        int r = idx >> 3, c8 = (idx & 7) << 3;
        bf16x8 v = *reinterpret_cast<const bf16x8*>(WT + (size_t)(n0 + r) * K + k0 + c8);
        *reinterpret_cast<bf16x8*>(&Bs[r][c8]) = v;
      }
    }
    // ---- stage A tile
    if (AMODE == 1 || AMODE == 3 || AMODE == 4) {
      int idx = tid;
      #pragma unroll
      for (int it = 0; it < 4; ++it, idx += 256) {
        int r = idx >> 3, c8 = (idx & 7) << 3;
        int row = m0 + r; if (row >= M) row = M - 1;
        size_t srow = (AMODE == 4) ? (size_t)eS[r] : (size_t)row;
        bf16x8 v = *reinterpret_cast<const bf16x8*>(Abf + srow * K + k0 + c8);
        if (AMODE == 1) {
          bf16x8 o;
          #pragma unroll
          for (int e = 0; e < 8; ++e) {
            int c = k0 + c8 + e;
            float f = sc_sh[c] * (float)v[e] + sh_sh[c];
            f = f >= 0.f ? f : 0.2f * f;
            o[e] = (bf16)f;
          }
          *reinterpret_cast<bf16x8*>(&As[r][c8]) = o;
        } else {
          *reinterpret_cast<bf16x8*>(&As[r][c8]) = v;
        }
      }
    } else {
      int idx = tid;
      #pragma unroll
      for (int it = 0; it < 8; ++it, idx += 256) {
        int r = idx >> 4, c4 = (idx & 15) << 2;
        int row = m0 + r; if (row >= M) row = M - 1;
        const float* src;
        float mul = 1.f;
        if (AMODE == 0) {
          int k = k0 + c4;
          if (k < 128)      src = obj  + (size_t)eS[r] * 128 + k;
          else if (k < 256) src = pred + (size_t)row * 128 + (k - 128);
          else              src = obj  + (size_t)eO[r] * 128 + (k - 256);
        } else {
          src = Af32 + (size_t)row * K + k0 + c4;
          mul = invcnt[row];
        }
        float4 v = *reinterpret_cast<const float4*>(src);
        As[r][c4 + 0] = (bf16)(v.x * mul);
        As[r][c4 + 1] = (bf16)(v.y * mul);
        As[r][c4 + 2] = (bf16)(v.z * mul);
        As[r][c4 + 3] = (bf16)(v.w * mul);
      }
    }
    __syncthreads();
    #pragma unroll
    for (int kk = 0; kk < BKT; kk += 32) {
      bf16x8 af[4], bfv[4];
      #pragma unroll
      for (int i = 0; i < 4; ++i)
        af[i] = *reinterpret_cast<const bf16x8*>(&As[wm + i * 16 + l15][kk + quad * 8]);
      #pragma unroll
      for (int j = 0; j < 4; ++j)
        bfv[j] = *reinterpret_cast<const bf16x8*>(&Bs[wn + j * 16 + l15][kk + quad * 8]);
      #pragma unroll
      for (int i = 0; i < 4; ++i)
        #pragma unroll
        for (int j = 0; j < 4; ++j)
          acc[i][j] = __builtin_amdgcn_mfma_f32_16x16x32_bf16(af[i], bfv[j], acc[i][j], 0, 0, 0);
    }
    __syncthreads();
  }

  if (EPI == 2) {
    #pragma unroll
    for (int i = 0; i < 4; ++i) {
      #pragma unroll
      for (int r = 0; r < 4; ++r) {
        int lrow = wm + i * 16 + quad * 4 + r;
        int row = m0 + lrow;
        if (row >= M) continue;
        #pragma unroll
        for (int j = 0; j < 4; ++j) {
          int cl = wn + j * 16 + l15;
          int n1 = n0 + cl;
          float v = osc[cl] * acc[i][j][r] + osh[cl];
          v = v >= 0.f ? v : 0.2f * v;
          if (n1 < 512)      atomicAdd(&pooled[(size_t)eS[lrow] * 512 + n1], v);
          else if (n1 < 640) outF[(size_t)row * 128 + (n1 - 512)] = v;
          else               atomicAdd(&pooled[(size_t)eO[lrow] * 512 + (n1 - 640)], v);
        }
      }
    }
  } else if (EPI == 4) {
    #pragma unroll
    for (int i = 0; i < 4; ++i) {
      #pragma unroll
      for (int r = 0; r < 4; ++r) {
        int lrow = wm + i * 16 + quad * 4 + r;
        int row = m0 + lrow;
        if (row >= M) continue;
        #pragma unroll
        for (int j = 0; j < 4; ++j) {
          int cl = wn + j * 16 + l15;
          int n1 = n0 + cl;
          float v = osc[cl] * acc[i][j][r] + osh[cl];
          v = v >= 0.f ? v : 0.2f * v;
          if (n1 < 512) outB[(size_t)(row - rbase) * 512 + n1] = (bf16)v;
          else          outF[(size_t)eS[lrow] * 128 + (n1 - 512)] = v;
        }
      }
    }
  } else {
    #pragma unroll
    for (int j = 0; j < 4; ++j) {
      float s = 0.f, q = 0.f;
      #pragma unroll
      for (int i = 0; i < 4; ++i) {
        #pragma unroll
        for (int r = 0; r < 4; ++r) {
          int row = m0 + wm + i * 16 + quad * 4 + r;
          if (row >= M) continue;
          float v = acc[i][j][r];
          s += v; q += v * v;
          int col = n0 + wn + j * 16 + l15;
          if (EPI == 0) outB[(size_t)row * N + col] = (bf16)v;
          if (EPI == 3) outF[(size_t)row * N + col] = v;
        }
      }
      s += __shfl_xor(s, 16); q += __shfl_xor(q, 16);
      s += __shfl_xor(s, 32); q += __shfl_xor(q, 32);
      if (quad == 0) {
        int col = n0 + wn + j * 16 + l15;
        atomicAdd(&gsum[col], s);
        atomicAdd(&gsq[col], q);
      }
    }
  }
}

// Segmented pooled accumulation: rows of buf are sorted by target object; object o
// owns contiguous sorted rows [rowptr[o], rowptr[o+1]). One wave per object sums the
// part of its range inside [rbase, rend) and does a non-atomic += into pooled.
__global__ __launch_bounds__(256) void gseg_k(const bf16* __restrict__ buf,
    const int* __restrict__ rowptr, float* __restrict__ pooled,
    int rbase, int rend, int O) {
  int o = blockIdx.x * 4 + (threadIdx.x >> 6);
  if (o >= O) return;
  int e0 = rowptr[o], e1 = rowptr[o + 1];
  int s = e0 > rbase ? e0 : rbase;
  int e = e1 < rend ? e1 : rend;
  if (s >= e) return;
  int lane = threadIdx.x & 63;
  int c0 = lane * 8;
  float acc[8];
  #pragma unroll
  for (int j = 0; j < 8; ++j) acc[j] = 0.f;
  for (int r = s; r < e; ++r) {
    bf16x8 v = *reinterpret_cast<const bf16x8*>(buf + (size_t)(r - rbase) * 512 + c0);
    #pragma unroll
    for (int j = 0; j < 8; ++j) acc[j] += (float)v[j];
  }
  float* dst = pooled + (size_t)o * 512 + c0;
  float4 a = *reinterpret_cast<float4*>(dst);
  float4 b = *reinterpret_cast<float4*>(dst + 4);
  a.x += acc[0]; a.y += acc[1]; a.z += acc[2]; a.w += acc[3];
  b.x += acc[4]; b.y += acc[5]; b.z += acc[6]; b.w += acc[7];
  *reinterpret_cast<float4*>(dst) = a;
  *reinterpret_cast<float4*>(dst + 4) = b;
}

// Gram matrix G = A2^T A2 (512x512 f32) over T rows. Upper-triangle tile pairs only
// (10 of 16); off-diagonal tiles mirror their result at write time. Split-K over T.
__global__ __launch_bounds__(256) void gram_k(const bf16* __restrict__ A2,
                                              float* __restrict__ G, int T) {
  __shared__ __align__(16) bf16 Ks[2][128][LDT];
  const int tid = threadIdx.x;
  const int tile = blockIdx.x % 10;
  const int s    = blockIdx.x / 10;
  const int NS   = gridDim.x / 10;
  const int K1T[10] = {0, 0, 0, 0, 1, 1, 1, 2, 2, 3};
  const int K2T[10] = {0, 1, 2, 3, 1, 2, 3, 2, 3, 3};
  const int k1b = K1T[tile], k2b = K2T[tile];
  const int lane = tid & 63;
  const int w = tid >> 6;
  const int wm = (w >> 1) * 64;
  const int wn = (w & 1) * 64;
  const int l15 = lane & 15;
  const int quad = lane >> 4;

  const int NG = (T + 63) >> 6;           // 64-row groups
  const int GPB = (NG + NS - 1) / NS;
  const int g0 = s * GPB;
  const int gend = min(NG, g0 + GPB);

  f32x4 acc[4][4];
  #pragma unroll
  for (int i = 0; i < 4; ++i)
    #pragma unroll
    for (int j = 0; j < 4; ++j)
      acc[i][j] = (f32x4){0.f, 0.f, 0.f, 0.f};

  const int bsel = (k1b == k2b) ? 0 : 1;

  for (int g = g0; g < gend; ++g) {
    const int t0 = g << 6;
    #pragma unroll
    for (int it = 0; it < 4; ++it) {
      int lin = it * 256 + tid;
      int t = lin >> 4, c8 = lin & 15;
      int row = t0 + t;
      bf16x8 v;
      #pragma unroll
      for (int e = 0; e < 8; ++e) v[e] = (bf16)0.f;
      if (row < T)
        v = *reinterpret_cast<const bf16x8*>(A2 + (size_t)row * 512 + k1b * 128 + c8 * 8);
      int ts = t ^ ((c8 & 7) << 3);
      #pragma unroll
      for (int e = 0; e < 8; ++e) Ks[0][c8 * 8 + e][ts] = v[e];
    }
    if (bsel) {
      #pragma unroll
      for (int it = 0; it < 4; ++it) {
        int lin = it * 256 + tid;
        int t = lin >> 4, c8 = lin & 15;
        int row = t0 + t;
        bf16x8 v;
        #pragma unroll
        for (int e = 0; e < 8; ++e) v[e] = (bf16)0.f;
        if (row < T)
          v = *reinterpret_cast<const bf16x8*>(A2 + (size_t)row * 512 + k2b * 128 + c8 * 8);
        int ts = t ^ ((c8 & 7) << 3);
        #pragma unroll
        for (int e = 0; e < 8; ++e) Ks[1][c8 * 8 + e][ts] = v[e];
      }
    }
    __syncthreads();
    #pragma unroll
    for (int kk = 0; kk < 64; kk += 32) {
      bf16x8 af[4], bfv[4];
      #pragma unroll
      for (int i = 0; i < 4; ++i) {
        int r = wm + i * 16 + l15;
        int toff = (kk + quad * 8) ^ (((r >> 3) & 7) << 3);
        af[i] = *reinterpret_cast<const bf16x8*>(&Ks[0][r][toff]);
      }
      #pragma unroll
      for (int j = 0; j < 4; ++j) {
        int r = wn + j * 16 + l15;
        int toff = (kk + quad * 8) ^ (((r >> 3) & 7) << 3);
        bfv[j] = *reinterpret_cast<const bf16x8*>(&Ks[bsel][r][toff]);
      }
      #pragma unroll
      for (int i = 0; i < 4; ++i)
        #pragma unroll
        for (int j = 0; j < 4; ++j)
          acc[i][j] = __builtin_amdgcn_mfma_f32_16x16x32_bf16(af[i], bfv[j], acc[i][j], 0, 0, 0);
    }
    __syncthreads();
  }

  #pragma unroll
  for (int i = 0; i < 4; ++i) {
    #pragma unroll
    for (int r = 0; r < 4; ++r) {
      int grow = k1b * 128 + wm + i * 16 + quad * 4 + r;
      #pragma unroll
      for (int j = 0; j < 4; ++j) {
        int gcol = k2b * 128 + wn + j * 16 + l15;
        float v = acc[i][j][r];
        atomicAdd(&G[(size_t)grow * 512 + gcol], v);
        if (k1b != k2b)
          atomicAdd(&G[(size_t)gcol * 512 + grow], v);
      }
    }
  }
}

// A2 = bn_lrelu(hA) in-place, fused with column sums of A2 (csum, f32[512]).
__global__ __launch_bounds__(256) void act_colsum_k(bf16* __restrict__ hA,
    const float* __restrict__ scale, const float* __restrict__ shift,
    float* __restrict__ csum, int T) {
  __shared__ float sh[4 * 512];
  const int tid = threadIdx.x;
  const int c0 = (tid & 63) * 8;
  const int rofs = tid >> 6;
  float sc[8], sf[8];
  #pragma unroll
  for (int j = 0; j < 8; ++j) { sc[j] = scale[c0 + j]; sf[j] = shift[c0 + j]; }
  float acc[8];
  #pragma unroll
  for (int j = 0; j < 8; ++j) acc[j] = 0.f;
  for (int r = blockIdx.x * 4 + rofs; r < T; r += gridDim.x * 4) {
    bf16x8 v = *reinterpret_cast<const bf16x8*>(hA + (size_t)r * 512 + c0);
    bf16x8 o;
    #pragma unroll
    for (int j = 0; j < 8; ++j) {
      float f = sc[j] * (float)v[j] + sf[j];
      f = f >= 0.f ? f : 0.2f * f;
      o[j] = (bf16)f;
      acc[j] += (float)o[j];   // accumulate the bf16-rounded value GEMM2 will see
    }
    *reinterpret_cast<bf16x8*>(hA + (size_t)r * 512 + c0) = o;
  }
  #pragma unroll
  for (int j = 0; j < 8; ++j) sh[rofs * 512 + c0 + j] = acc[j];
  __syncthreads();
  for (int c = tid; c < 512; c += 256) {
    float s = sh[c] + sh[512 + c] + sh[1024 + c] + sh[1536 + c];
    atomicAdd(&csum[c], s);
  }
}

// Per output column c of GEMM2: sumB[c] = csum . W1b[:,c],
// sqB[c] = W1b[:,c]^T G W1b[:,c]. One block per 4 columns.
__global__ __launch_bounds__(256) void colstat_k(const float* __restrict__ G,
    const float* __restrict__ csum, const float* __restrict__ W1b,
    float* __restrict__ sumB, float* __restrict__ sqB) {
  __shared__ float wL[4][512];
  __shared__ float rq[4][4], rs[4][4];
  const int tid = threadIdx.x;
  const int c0 = blockIdx.x * 4;
  for (int idx = tid; idx < 2048; idx += 256) {
    int c = idx >> 9, k = idx & 511;
    wL[c][k] = W1b[(size_t)k * 1152 + c0 + c];
  }
  __syncthreads();
  float pq[4] = {0.f, 0.f, 0.f, 0.f};
  float ps[4] = {0.f, 0.f, 0.f, 0.f};
  for (int e = tid; e < 512 * 512; e += 256) {
    int i = e >> 9, j = e & 511;
    float g = G[e];
    #pragma unroll
    for (int c = 0; c < 4; ++c) pq[c] += g * wL[c][i] * wL[c][j];
  }
  for (int k = tid; k < 512; k += 256) {
    float cs = csum[k];
    #pragma unroll
    for (int c = 0; c < 4; ++c) ps[c] += cs * wL[c][k];
  }
  #pragma unroll
  for (int c = 0; c < 4; ++c) {
    #pragma unroll
    for (int off = 32; off > 0; off >>= 1) {
      pq[c] += __shfl_xor(pq[c], off);
      ps[c] += __shfl_xor(ps[c], off);
    }
  }
  const int w = tid >> 6, lane = tid & 63;
  if (lane == 0) {
    #pragma unroll
    for (int c = 0; c < 4; ++c) { rq[w][c] = pq[c]; rs[w][c] = ps[c]; }
  }
  __syncthreads();
  if (tid < 4) {
    sqB[c0 + tid]  = rq[0][tid] + rq[1][tid] + rq[2][tid] + rq[3][tid];
    sumB[c0 + tid] = rs[0][tid] + rs[1][tid] + rs[2][tid] + rs[3][tid];
  }
}

// transpose + fp32->bf16 convert: W (K,N) -> WT (N,K)
__global__ __launch_bounds__(256) void tconv_k(const float* __restrict__ W,
                                               bf16* __restrict__ WT, int K, int N) {
  int idx = blockIdx.x * 256 + threadIdx.x;
  if (idx < K * N) {
    int n = idx / K, k = idx - n * K;
    WT[(size_t)n * K + k] = (bf16)W[(size_t)k * N + n];
  }
}

__global__ __launch_bounds__(256) void bnfin_k(const float* __restrict__ sum,
    const float* __restrict__ sq, const float* __restrict__ g,
    const float* __restrict__ be, float* __restrict__ scale,
    float* __restrict__ shift, int C, float invR) {
  int c = blockIdx.x * 256 + threadIdx.x;
  if (c < C) {
    float m = sum[c] * invR;
    float v = sq[c] * invR - m * m;
    float a = g[c] * rsqrtf(v + 1e-5f);
    scale[c] = a;
    shift[c] = be[c] - m * a;
  }
}

// per-role edge counts
__global__ __launch_bounds__(256) void cnt2_k(const int* __restrict__ edges,
    int* __restrict__ cntS, int* __restrict__ cntO, int T) {
  int t = blockIdx.x * 256 + threadIdx.x;
  if (t < T) {
    atomicAdd(&cntS[edges[2 * t]], 1);
    atomicAdd(&cntO[edges[2 * t + 1]], 1);
  }
}

__global__ __launch_bounds__(256) void invcnt2_k(const int* __restrict__ cntS,
    const int* __restrict__ cntO, float* __restrict__ invc, int O) {
  int i = blockIdx.x * 256 + threadIdx.x;
  if (i < O) {
    float c = fminf(fmaxf((float)(cntS[i] + cntO[i]), 1.f), (float)O);
    invc[i] = 1.f / c;
  }
}

// single-block exclusive scan of cntA(+cntB) -> rowptr, head
__global__ __launch_bounds__(1024) void scan_k(const int* __restrict__ cntA,
    const int* __restrict__ cntB,
    int* __restrict__ rowptr, int* __restrict__ head, int O, int total) {
  __shared__ int sh[1024];
  const int t = threadIdx.x;
  const int C = (O + 1023) / 1024;
  const int i0 = t * C;
  int s = 0;
  for (int i = 0; i < C; ++i) {
    int idx = i0 + i;
    if (idx < O) s += cntA[idx] + (cntB ? cntB[idx] : 0);
  }
  sh[t] = s;
  __syncthreads();
  for (int d = 1; d < 1024; d <<= 1) {
    int v = (t >= d) ? sh[t - d] : 0;
    __syncthreads();
    sh[t] += v;
    __syncthreads();
  }
  int run = (t == 0) ? 0 : sh[t - 1];
  for (int i = 0; i < C; ++i) {
    int idx = i0 + i;
    if (idx < O) {
      rowptr[idx] = run;
      head[idx] = run;
      run += cntA[idx] + (cntB ? cntB[idx] : 0);
    }
  }
  if (t == 0) rowptr[O] = total;
}

// staged-path fill: combined role-tagged incidence list
__global__ __launch_bounds__(256) void fill_k(const int* __restrict__ edges,
    int* __restrict__ head, int* __restrict__ list, int T) {
  int t = blockIdx.x * 256 + threadIdx.x;
  if (t < T) {
    int s = edges[2 * t];
    int p = atomicAdd(&head[s], 1);
    list[p] = t << 1;
    int o = edges[2 * t + 1];
    p = atomicAdd(&head[o], 1);
    list[p] = (t << 1) | 1;
  }
}

// sorted-path fill: per-role permutations (t sorted by target object)
__global__ __launch_bounds__(256) void fill2_k(const int* __restrict__ edges,
    int* __restrict__ headS, int* __restrict__ headO,
    int* __restrict__ permS, int* __restrict__ permO, int T) {
  int t = blockIdx.x * 256 + threadIdx.x;
  if (t < T) {
    int s = edges[2 * t];
    int p = atomicAdd(&headS[s], 1);
    permS[p] = t;
    int o = edges[2 * t + 1];
    int q = atomicAdd(&headO[o], 1);
    permO[q] = t;
  }
}

// in-place A2 = bn_lrelu(hA)  (staged path)
__global__ __launch_bounds__(256) void act_k(bf16* __restrict__ hA,
    const float* __restrict__ scale, const float* __restrict__ shift, size_t n8) {
  size_t i = (size_t)blockIdx.x * 256 + threadIdx.x;
  if (i < n8) {
    size_t idx8 = i * 8;
    int c = (int)(idx8 & 511);
    bf16x8 v = *reinterpret_cast<const bf16x8*>(hA + idx8);
    bf16x8 o;
    #pragma unroll
    for (int j = 0; j < 8; ++j) {
      float f = scale[c + j] * (float)v[j] + shift[c + j];
      f = f >= 0.f ? f : 0.2f * f;
      o[j] = (bf16)f;
    }
    *reinterpret_cast<bf16x8*>(hA + idx8) = o;
  }
}

// new_p = bn_lrelu(tB[:,512:640]) -> out_p f32  (staged path)
__global__ __launch_bounds__(256) void newp_k(const bf16* __restrict__ tB,
    const float* __restrict__ scale, const float* __restrict__ shift,
    float* __restrict__ outP, int T) {
  int i = blockIdx.x * 256 + threadIdx.x;
  if (i < T * 128) {
    int t = i >> 7, c = i & 127;
    float v = scale[512 + c] * (float)tB[(size_t)t * 1152 + 512 + c] + shift[512 + c];
    outP[i] = v >= 0.f ? v : 0.2f * v;
  }
}

// staged path gather from full tB
__global__ __launch_bounds__(256) void gather_k(const bf16* __restrict__ tB,
    const int* __restrict__ rowptr, const int* __restrict__ list,
    const float* __restrict__ scale, const float* __restrict__ shift,
    const float* __restrict__ invc, bf16* __restrict__ pooled, int O) {
  int o = blockIdx.x * 4 + (threadIdx.x >> 6);
  if (o >= O) return;
  int lane = threadIdx.x & 63;
  int c0 = lane * 8;
  float scS[8], shS[8], scO[8], shO[8];
  #pragma unroll
  for (int j = 0; j < 8; ++j) {
    scS[j] = scale[c0 + j];       shS[j] = shift[c0 + j];
    scO[j] = scale[640 + c0 + j]; shO[j] = shift[640 + c0 + j];
  }
  float acc[8];
  #pragma unroll
  for (int j = 0; j < 8; ++j) acc[j] = 0.f;
  int e0 = rowptr[o], e1 = rowptr[o + 1];
  for (int e = e0; e < e1; ++e) {
    int id = list[e];
    int t = id >> 1;
    int role = id & 1;
    const bf16* row = tB + (size_t)t * 1152 + (role ? 640 : 0) + c0;
    bf16x8 v = *reinterpret_cast<const bf16x8*>(row);
    if (role) {
      #pragma unroll
      for (int j = 0; j < 8; ++j) {
        float f = scO[j] * (float)v[j] + shO[j];
        acc[j] += (f >= 0.f ? f : 0.2f * f);
      }
    } else {
      #pragma unroll
      for (int j = 0; j < 8; ++j) {
        float f = scS[j] * (float)v[j] + shS[j];
        acc[j] += (f >= 0.f ? f : 0.2f * f);
      }
    }
  }
  float ic = invc[o];
  bf16x8 out;
  #pragma unroll
  for (int j = 0; j < 8; ++j) out[j] = (bf16)(acc[j] * ic);
  *reinterpret_cast<bf16x8*>(pooled + (size_t)o * 512 + c0) = out;
}

__global__ __launch_bounds__(256) void final_k(float* __restrict__ buf,
    const float* __restrict__ scale, const float* __restrict__ shift, int n) {
  int i = blockIdx.x * 256 + threadIdx.x;
  if (i < n) {
    int c = i & 127;
    float v = scale[c] * buf[i] + shift[c];
    buf[i] = v >= 0.f ? v : 0.2f * v;
  }
}

extern "C" void kernel_launch(void* const* d_in, const int* in_sizes, int n_in,
                              void* d_out, int out_size, void* d_ws, size_t ws_size,
                              hipStream_t stream) {
  const float* obj   = (const float*)d_in[0];
  const float* pred  = (const float*)d_in[1];
  const int*   edges = (const int*)d_in[2];
  const float* W1a = (const float*)d_in[3];
  const float* g1a = (const float*)d_in[5];
  const float* be1a= (const float*)d_in[6];
  const float* W1b = (const float*)d_in[7];
  const float* g1b = (const float*)d_in[9];
  const float* be1b= (const float*)d_in[10];
  const float* W2a = (const float*)d_in[11];
  const float* g2a = (const float*)d_in[13];
  const float* be2a= (const float*)d_in[14];
  const float* W2b = (const float*)d_in[15];
  const float* g2b = (const float*)d_in[17];
  const float* be2b= (const float*)d_in[18];

  const int O = in_sizes[0] / 128;
  const int T = in_sizes[1] / 128;
  float* out_obj = (float*)d_out;
  float* out_p   = (float*)d_out + (size_t)O * 128;

  char* base = (char*)d_ws;
  size_t off = 0;
  auto alloc = [&](size_t bytes) { size_t p = off; off += (bytes + 255) & ~(size_t)255; return p; };
  size_t oWT1a = alloc((size_t)384 * 512 * 2);
  size_t oWT1b = alloc((size_t)512 * 1152 * 2);
  size_t oWT2a = alloc((size_t)512 * 512 * 2);
  size_t oWT2b = alloc((size_t)512 * 128 * 2);
  size_t oSums = alloc(4608 * 4);
  size_t oScl  = alloc(4608 * 4);
  size_t oG    = alloc((size_t)512 * 512 * 4);
  size_t oCsum = alloc(512 * 4);
  size_t oCntS = alloc((size_t)O * 4);
  size_t oCntO = alloc((size_t)O * 4);
  size_t oInvc = alloc((size_t)O * 4);
  size_t oRpS  = alloc((size_t)(O + 1) * 4);
  size_t oRpO  = alloc((size_t)(O + 1) * 4);
  size_t oHdS  = alloc((size_t)O * 4);
  size_t oHdO  = alloc((size_t)O * 4);
  size_t oPmS  = alloc((size_t)T * 4);
  size_t oPmO  = alloc((size_t)T * 4);
  size_t oList = alloc((size_t)2 * T * 4);      // staged path incidence list
  size_t oHA   = alloc((size_t)T * 512 * 2);    // hA/A2 bf16; h2 aliases later
  size_t oBig  = off;                           // staged: tB; fallback: pooledF f32

  size_t need_staged = oBig + (((size_t)T * 1152 * 2 + 255) & ~(size_t)255)
                            + (size_t)O * 512 * 2;
  const bool staged = (ws_size >= need_staged);

  // sorted-chunk tier: pooledF f32 + bf16 chunk buffer after it
  size_t oPool = oBig;
  size_t oBuf  = oPool + (((size_t)O * 512 * 4 + 255) & ~(size_t)255);
  int chunkT = 0;
  if (!staged && ws_size > oBuf) {
    size_t avail = ws_size - oBuf;
    size_t ct = avail / ((size_t)512 * 2);
    if (ct > (size_t)T) ct = T;
    chunkT = (int)(ct & ~(size_t)127);
  }
  const bool sorted = (!staged && chunkT >= 4096);

  bf16* WT1a = (bf16*)(base + oWT1a);
  bf16* WT1b = (bf16*)(base + oWT1b);
  bf16* WT2a = (bf16*)(base + oWT2a);
  bf16* WT2b = (bf16*)(base + oWT2b);
  float* sums = (float*)(base + oSums);
  float* sumA = sums,        * sqA = sums + 512;
  float* sumB = sums + 1024, * sqB = sums + 2176;
  float* sumC = sums + 3328, * sqC = sums + 3840;
  float* sumD = sums + 4352, * sqD = sums + 4480;
  float* scl = (float*)(base + oScl);
  float* scaleA = scl,        * shiftA = scl + 512;
  float* scaleB = scl + 1024, * shiftB = scl + 2176;
  float* scaleC = scl + 3328, * shiftC = scl + 3840;
  float* scaleD = scl + 4352, * shiftD = scl + 4480;
  float* Gm   = (float*)(base + oG);
  float* csum = (float*)(base + oCsum);
  int*   cntS = (int*)(base + oCntS);
  int*   cntO = (int*)(base + oCntO);
  float* invc = (float*)(base + oInvc);
  int*   rpS  = (int*)(base + oRpS);
  int*   rpO  = (int*)(base + oRpO);
  int*   hdS  = (int*)(base + oHdS);
  int*   hdO  = (int*)(base + oHdO);
  int*   permS= (int*)(base + oPmS);
  int*   permO= (int*)(base + oPmO);
  int*   list = (int*)(base + oList);
  bf16*  hA = (bf16*)(base + oHA);     // also A2 (in-place), later h2
  bf16*  h2 = (bf16*)(base + oHA);
  bf16*  tB = (bf16*)(base + oBig);
  bf16*  pooledB = (bf16*)(base + oBig + (((size_t)T * 1152 * 2 + 255) & ~(size_t)255));
  float* pooledF = (float*)(base + oPool);
  bf16*  bufS = (bf16*)(base + oBuf);
  float* objpre = out_obj;

  hipMemsetAsync(sums, 0, 4608 * 4, stream);
  hipMemsetAsync(cntS, 0, (size_t)O * 4, stream);
  hipMemsetAsync(cntO, 0, (size_t)O * 4, stream);
  if (!staged) {
    hipMemsetAsync(Gm, 0, (size_t)512 * 512 * 4, stream);
    hipMemsetAsync(csum, 0, 512 * 4, stream);
    hipMemsetAsync(pooledF, 0, (size_t)O * 512 * 4, stream);
  }

  tconv_k<<<(384 * 512 + 255) / 256, 256, 0, stream>>>(W1a, WT1a, 384, 512);
  tconv_k<<<(512 * 1152 + 255) / 256, 256, 0, stream>>>(W1b, WT1b, 512, 1152);
  tconv_k<<<(512 * 512 + 255) / 256, 256, 0, stream>>>(W2a, WT2a, 512, 512);
  tconv_k<<<(512 * 128 + 255) / 256, 256, 0, stream>>>(W2b, WT2b, 512, 128);
  cnt2_k<<<(T + 255) / 256, 256, 0, stream>>>(edges, cntS, cntO, T);
  invcnt2_k<<<(O + 255) / 256, 256, 0, stream>>>(cntS, cntO, invc, O);
  if (staged) {
    scan_k<<<1, 1024, 0, stream>>>(cntS, cntO, rpS, hdS, O, 2 * T);
    fill_k<<<(T + 255) / 256, 256, 0, stream>>>(edges, hdS, list, T);
  } else if (sorted) {
    scan_k<<<1, 1024, 0, stream>>>(cntS, nullptr, rpS, hdS, O, T);
    scan_k<<<1, 1024, 0, stream>>>(cntO, nullptr, rpO, hdO, O, T);
    fill2_k<<<(T + 255) / 256, 256, 0, stream>>>(edges, hdS, hdO, permS, permO, T);
  }

  const int Tb = (T + BM - 1) / BM;
  const int Ob = (O + BM - 1) / BM;

  // GEMM1: gathered (T,384) @ W1a -> hA raw bf16 + statsA
  {
    dim3 g(512 / BN, Tb);
    gemm_k<0, 0><<<g, 256, 0, stream>>>(nullptr, nullptr, obj, pred, edges, nullptr,
        nullptr, nullptr, nullptr, nullptr, WT1a, hA, nullptr, nullptr, sumA, sqA,
        T, 512, 384, nullptr, 0);
  }
  bnfin_k<<<2, 256, 0, stream>>>(sumA, sqA, g1a, be1a, scaleA, shiftA, 512, 1.f / T);

  if (staged) {
    act_k<<<(int)(((size_t)T * 512 / 8 + 255) / 256), 256, 0, stream>>>(hA, scaleA,
        shiftA, (size_t)T * 512 / 8);
    {
      dim3 g(1152 / BN, Tb);
      gemm_k<3, 0><<<g, 256, 0, stream>>>(hA, nullptr, nullptr, nullptr, nullptr, nullptr,
          nullptr, nullptr, nullptr, nullptr, WT1b, tB, nullptr, nullptr, sumB, sqB,
          T, 1152, 512, nullptr, 0);
    }
    bnfin_k<<<5, 256, 0, stream>>>(sumB, sqB, g1b, be1b, scaleB, shiftB, 1152, 1.f / T);
    newp_k<<<(T * 128 + 255) / 256, 256, 0, stream>>>(tB, scaleB, shiftB, out_p, T);
    gather_k<<<(O + 3) / 4, 256, 0, stream>>>(tB, rpS, list, scaleB, shiftB, invc,
        pooledB, O);
    {
      dim3 g(512 / BN, Ob);
      gemm_k<3, 0><<<g, 256, 0, stream>>>(pooledB, nullptr, nullptr, nullptr, nullptr,
          nullptr, nullptr, nullptr, nullptr, nullptr, WT2a, h2, nullptr, nullptr,
          sumC, sqC, O, 512, 512, nullptr, 0);
    }
  } else {
    // stats via colsum + Gram (no full stats GEMM pass)
    act_colsum_k<<<1024, 256, 0, stream>>>(hA, scaleA, shiftA, csum, T);
    gram_k<<<10 * 48, 256, 0, stream>>>(hA, Gm, T);
    colstat_k<<<288, 256, 0, stream>>>(Gm, csum, W1b, sumB, sqB);
    bnfin_k<<<5, 256, 0, stream>>>(sumB, sqB, g1b, be1b, scaleB, shiftB, 1152, 1.f / T);

    if (sorted) {
      // pass S: rows sorted by subject; cols 0..511 -> chunk buf, 512..639 -> new_p
      for (int c0 = 0; c0 < T; c0 += chunkT) {
        int c1 = min(T, c0 + chunkT);
        dim3 g(5, (c1 - c0 + BM - 1) / BM);
        gemm_k<4, 4><<<g, 256, 0, stream>>>(hA, nullptr, nullptr, nullptr, nullptr,
            nullptr, nullptr, nullptr, scaleB, shiftB, WT1b, bufS, out_p, nullptr,
            nullptr, nullptr, c1, 640, 512, permS, c0);
        gseg_k<<<(O + 3) / 4, 256, 0, stream>>>(bufS, rpS, pooledF, c0, c1, O);
      }
      // pass O: rows sorted by object; cols 640..1151 -> chunk buf
      for (int c0 = 0; c0 < T; c0 += chunkT) {
        int c1 = min(T, c0 + chunkT);
        dim3 g(4, (c1 - c0 + BM - 1) / BM);
        gemm_k<4, 4><<<g, 256, 0, stream>>>(hA, nullptr, nullptr, nullptr, nullptr,
            nullptr, nullptr, nullptr, scaleB + 640, shiftB + 640,
            WT1b + (size_t)640 * 512, bufS, out_p, nullptr,
            nullptr, nullptr, c1, 512, 512, permO, c0);
        gseg_k<<<(O + 3) / 4, 256, 0, stream>>>(bufS, rpO, pooledF, c0, c1, O);
      }
    } else {
      // tier-3: single GEMM2 pass with atomic scatter (round-1 behavior)
      dim3 g(1152 / BN, Tb);
      gemm_k<3, 2><<<g, 256, 0, stream>>>(hA, nullptr, nullptr, nullptr, edges, nullptr,
          nullptr, nullptr, scaleB, shiftB, WT1b, nullptr, out_p, pooledF, nullptr,
          nullptr, T, 1152, 512, nullptr, 0);
    }
    // GEMM3: (pooledF * invc) (O,512) @ W2a -> h2 bf16 + statsC
    {
      dim3 g(512 / BN, Ob);
      gemm_k<2, 0><<<g, 256, 0, stream>>>(nullptr, pooledF, nullptr, nullptr, nullptr,
          invc, nullptr, nullptr, nullptr, nullptr, WT2a, h2, nullptr, nullptr,
          sumC, sqC, O, 512, 512, nullptr, 0);
    }
  }
  bnfin_k<<<2, 256, 0, stream>>>(sumC, sqC, g2a, be2a, scaleC, shiftC, 512, 1.f / O);

  // GEMM4: bn_lrelu(h2) (O,512) @ W2b -> objpre f32 (in d_out) + statsD
  {
    dim3 g(128 / BN, Ob);
    gemm_k<1, 3><<<g, 256, 0, stream>>>(h2, nullptr, nullptr, nullptr, nullptr, nullptr,
        scaleC, shiftC, nullptr, nullptr, WT2b, nullptr, objpre, nullptr, sumD, sqD,
        O, 128, 512, nullptr, 0);
  }
  bnfin_k<<<1, 256, 0, stream>>>(sumD, sqD, g2b, be2b, scaleD, shiftD, 128, 1.f / O);

  final_k<<<((size_t)O * 128 + 255) / 256, 256, 0, stream>>>(objpre, scaleD, shiftD,
      (int)((size_t)O * 128));
}

// Round 3
// 2225.702 us; speedup vs baseline: 1.0178x; 1.0178x over previous
//
#include <hip/hip_runtime.h>

typedef __bf16 bf16;
typedef __bf16 bf16x8 __attribute__((ext_vector_type(8)));
typedef float  f32x4  __attribute__((ext_vector_type(4)));

#define BM 128
#define BN 128
#define BKT 64
#define LDK (BKT + 8)
#define LDT 72   // gram LDS row stride (t-dim padded)

// AMODE: 0 = gather concat [obj[s] | pred | obj[o]] (f32 -> bf16)
//        1 = bn_lrelu(scale*x+shift) applied to bf16 source
//        2 = f32 source * invcnt[row]
//        3 = plain bf16 copy
// EPI:   0 = store bf16 + column stats atomics
//        2 = bn_lrelu(out-col scale/shift) then atomic scatter (tier-3 fallback)
//        3 = store f32 + column stats atomics
//        5 = bn_lrelu(out-col scale/shift); cols<512 -> buf[(row-rbase)*1024 + n1] bf16,
//            512..639 -> outF[row*128+..] (new_p f32), >=640 -> buf[.. + n1-128] bf16
// Block swizzle: the NX column-blocks of one row panel are remapped to dispatch
// indices congruent mod 8 -> same XCD L2 -> A panel fetched once per XCD.
template<int AMODE, int EPI>
__global__ __launch_bounds__(256) void gemm_k(
    const bf16* __restrict__ Abf, const float* __restrict__ Af32,
    const float* __restrict__ obj, const float* __restrict__ pred,
    const int* __restrict__ edges, const float* __restrict__ invcnt,
    const float* __restrict__ scale, const float* __restrict__ shift,   // input-col bn (AMODE==1)
    const float* __restrict__ oscale, const float* __restrict__ oshift, // output-col bn (EPI==2/5)
    const bf16* __restrict__ WT,      // (N,K) bf16, pre-transposed
    bf16* __restrict__ outB, float* __restrict__ outF,
    float* __restrict__ pooled, float* __restrict__ gsum, float* __restrict__ gsq,
    int M, int N, int K, int rbase)
{
  __shared__ __align__(16) bf16 As[BM][LDK];
  __shared__ __align__(16) bf16 Bs[BN][LDK];
  __shared__ float sc_sh[(AMODE == 1) ? 512 : 1];
  __shared__ float sh_sh[(AMODE == 1) ? 512 : 1];
  __shared__ float osc[(EPI == 2 || EPI == 5) ? BN : 1];
  __shared__ float osh[(EPI == 2 || EPI == 5) ? BN : 1];
  __shared__ int eS[(AMODE == 0 || EPI == 2) ? BM : 1];
  __shared__ int eO[(AMODE == 0 || EPI == 2) ? BM : 1];

  const int tid = threadIdx.x;

  // ---- XCD-aligned swizzle (bijective; tail handled linearly)
  int bx = blockIdx.x, by = blockIdx.y;
  {
    const int NX = gridDim.x, NY = gridDim.y;
    int L = by * NX + bx;
    int bpg = NX * 8;
    int nFull = NY >> 3;
    int Lfull = nFull * bpg;
    if (L < Lfull) {
      int g = L / bpg, w2 = L - g * bpg;
      by = (g << 3) + (w2 & 7);
      bx = w2 >> 3;
    } else {
      int r2 = L - Lfull;
      int q = r2 / NX;
      by = (nFull << 3) + q;
      bx = r2 - q * NX;
    }
  }
  const int m0 = rbase + by * BM;
  const int n0 = bx * BN;

  const int lane = tid & 63;
  const int w = tid >> 6;
  const int wm = (w >> 1) * 64;
  const int wn = (w & 1) * 64;
  const int l15 = lane & 15;
  const int quad = lane >> 4;

  if (AMODE == 1) {
    for (int c = tid; c < K; c += 256) { sc_sh[c] = scale[c]; sh_sh[c] = shift[c]; }
  }
  if (EPI == 2 || EPI == 5) {
    if (tid < BN) { osc[tid] = oscale[n0 + tid]; osh[tid] = oshift[n0 + tid]; }
  }
  if (AMODE == 0 || EPI == 2) {
    if (tid < BM) {
      int r = m0 + tid; if (r >= M) r = M - 1;
      eS[tid] = edges[2 * r];
      eO[tid] = edges[2 * r + 1];
    }
  }
  __syncthreads();

  f32x4 acc[4][4];
  #pragma unroll
  for (int i = 0; i < 4; ++i)
    #pragma unroll
    for (int j = 0; j < 4; ++j)
      acc[i][j] = (f32x4){0.f, 0.f, 0.f, 0.f};

  for (int k0 = 0; k0 < K; k0 += BKT) {
    // ---- stage B^T tile
    {
      int idx = tid;
      #pragma unroll
      for (int it = 0; it < 4; ++it, idx += 256) {
        int r = idx >> 3, c8 = (idx & 7) << 3;
        bf16x8 v = *reinterpret_cast<const bf16x8*>(WT + (size_t)(n0 + r) * K + k0 + c8);
        *reinterpret_cast<bf16x8*>(&Bs[r][c8]) = v;
      }
    }
    // ---- stage A tile
    if (AMODE == 1 || AMODE == 3) {
      int idx = tid;
      #pragma unroll
      for (int it = 0; it < 4; ++it, idx += 256) {
        int r = idx >> 3, c8 = (idx & 7) << 3;
        int row = m0 + r; if (row >= M) row = M - 1;
        bf16x8 v = *reinterpret_cast<const bf16x8*>(Abf + (size_t)row * K + k0 + c8);
        if (AMODE == 1) {
          bf16x8 o;
          #pragma unroll
          for (int e = 0; e < 8; ++e) {
            int c = k0 + c8 + e;
            float f = sc_sh[c] * (float)v[e] + sh_sh[c];
            f = f >= 0.f ? f : 0.2f * f;
            o[e] = (bf16)f;
          }
          *reinterpret_cast<bf16x8*>(&As[r][c8]) = o;
        } else {
          *reinterpret_cast<bf16x8*>(&As[r][c8]) = v;
        }
      }
    } else {
      int idx = tid;
      #pragma unroll
      for (int it = 0; it < 8; ++it, idx += 256) {
        int r = idx >> 4, c4 = (idx & 15) << 2;
        int row = m0 + r; if (row >= M) row = M - 1;
        const float* src;
        float mul = 1.f;
        if (AMODE == 0) {
          int k = k0 + c4;
          if (k < 128)      src = obj  + (size_t)eS[r] * 128 + k;
          else if (k < 256) src = pred + (size_t)row * 128 + (k - 128);
          else              src = obj  + (size_t)eO[r] * 128 + (k - 256);
        } else {
          src = Af32 + (size_t)row * K + k0 + c4;
          mul = invcnt[row];
        }
        float4 v = *reinterpret_cast<const float4*>(src);
        As[r][c4 + 0] = (bf16)(v.x * mul);
        As[r][c4 + 1] = (bf16)(v.y * mul);
        As[r][c4 + 2] = (bf16)(v.z * mul);
        As[r][c4 + 3] = (bf16)(v.w * mul);
      }
    }
    __syncthreads();
    #pragma unroll
    for (int kk = 0; kk < BKT; kk += 32) {
      bf16x8 af[4], bfv[4];
      #pragma unroll
      for (int i = 0; i < 4; ++i)
        af[i] = *reinterpret_cast<const bf16x8*>(&As[wm + i * 16 + l15][kk + quad * 8]);
      #pragma unroll
      for (int j = 0; j < 4; ++j)
        bfv[j] = *reinterpret_cast<const bf16x8*>(&Bs[wn + j * 16 + l15][kk + quad * 8]);
      #pragma unroll
      for (int i = 0; i < 4; ++i)
        #pragma unroll
        for (int j = 0; j < 4; ++j)
          acc[i][j] = __builtin_amdgcn_mfma_f32_16x16x32_bf16(af[i], bfv[j], acc[i][j], 0, 0, 0);
    }
    __syncthreads();
  }

  if (EPI == 2) {
    #pragma unroll
    for (int i = 0; i < 4; ++i) {
      #pragma unroll
      for (int r = 0; r < 4; ++r) {
        int lrow = wm + i * 16 + quad * 4 + r;
        int row = m0 + lrow;
        if (row >= M) continue;
        #pragma unroll
        for (int j = 0; j < 4; ++j) {
          int cl = wn + j * 16 + l15;
          int n1 = n0 + cl;
          float v = osc[cl] * acc[i][j][r] + osh[cl];
          v = v >= 0.f ? v : 0.2f * v;
          if (n1 < 512)      atomicAdd(&pooled[(size_t)eS[lrow] * 512 + n1], v);
          else if (n1 < 640) outF[(size_t)row * 128 + (n1 - 512)] = v;
          else               atomicAdd(&pooled[(size_t)eO[lrow] * 512 + (n1 - 640)], v);
        }
      }
    }
  } else if (EPI == 5) {
    #pragma unroll
    for (int i = 0; i < 4; ++i) {
      #pragma unroll
      for (int r = 0; r < 4; ++r) {
        int lrow = wm + i * 16 + quad * 4 + r;
        int row = m0 + lrow;
        if (row >= M) continue;
        #pragma unroll
        for (int j = 0; j < 4; ++j) {
          int cl = wn + j * 16 + l15;
          int n1 = n0 + cl;
          float v = osc[cl] * acc[i][j][r] + osh[cl];
          v = v >= 0.f ? v : 0.2f * v;
          if (n1 < 512)      outB[(size_t)(row - rbase) * 1024 + n1] = (bf16)v;
          else if (n1 < 640) outF[(size_t)row * 128 + (n1 - 512)] = v;
          else               outB[(size_t)(row - rbase) * 1024 + (n1 - 128)] = (bf16)v;
        }
      }
    }
  } else {
    #pragma unroll
    for (int j = 0; j < 4; ++j) {
      float s = 0.f, q = 0.f;
      #pragma unroll
      for (int i = 0; i < 4; ++i) {
        #pragma unroll
        for (int r = 0; r < 4; ++r) {
          int row = m0 + wm + i * 16 + quad * 4 + r;
          if (row >= M) continue;
          float v = acc[i][j][r];
          s += v; q += v * v;
          int col = n0 + wn + j * 16 + l15;
          if (EPI == 0) outB[(size_t)row * N + col] = (bf16)v;
          if (EPI == 3) outF[(size_t)row * N + col] = v;
        }
      }
      s += __shfl_xor(s, 16); q += __shfl_xor(q, 16);
      s += __shfl_xor(s, 32); q += __shfl_xor(q, 32);
      if (quad == 0) {
        int col = n0 + wn + j * 16 + l15;
        atomicAdd(&gsum[col], s);
        atomicAdd(&gsq[col], q);
      }
    }
  }
}

// Chunked CSR pooling: one wave per object scans its role-tagged edge list,
// accumulates bn-activated rows with t in [c0,c1) from the dense chunk buffer
// (row layout: [s-part 512 | o-part 512] bf16), then non-atomic += into pooled.
__global__ __launch_bounds__(256) void gatherc_k(const bf16* __restrict__ buf,
    const int* __restrict__ rowptr, const int* __restrict__ list,
    float* __restrict__ pooled, int c0, int c1, int O) {
  int o = blockIdx.x * 4 + (threadIdx.x >> 6);
  if (o >= O) return;
  int lane = threadIdx.x & 63;
  int cc = lane * 8;
  int e0 = rowptr[o], e1 = rowptr[o + 1];
  float acc[8];
  #pragma unroll
  for (int j = 0; j < 8; ++j) acc[j] = 0.f;
  bool any = false;
  for (int e = e0; e < e1; ++e) {
    int id = list[e];
    int t = id >> 1;
    if (t < c0 || t >= c1) continue;
    const bf16* row = buf + (size_t)(t - c0) * 1024 + (id & 1) * 512 + cc;
    bf16x8 v = *reinterpret_cast<const bf16x8*>(row);
    #pragma unroll
    for (int j = 0; j < 8; ++j) acc[j] += (float)v[j];
    any = true;
  }
  if (!any) return;
  float* dst = pooled + (size_t)o * 512 + cc;
  float4 a = *reinterpret_cast<float4*>(dst);
  float4 b = *reinterpret_cast<float4*>(dst + 4);
  a.x += acc[0]; a.y += acc[1]; a.z += acc[2]; a.w += acc[3];
  b.x += acc[4]; b.y += acc[5]; b.z += acc[6]; b.w += acc[7];
  *reinterpret_cast<float4*>(dst) = a;
  *reinterpret_cast<float4*>(dst + 4) = b;
}

// Gram matrix G = A2^T A2 (512x512 f32) over T rows. Upper-triangle tile pairs only
// (10 of 16); off-diagonal tiles mirror their result at write time. Split-K over T.
__global__ __launch_bounds__(256) void gram_k(const bf16* __restrict__ A2,
                                              float* __restrict__ G, int T) {
  __shared__ __align__(16) bf16 Ks[2][128][LDT];
  const int tid = threadIdx.x;
  const int tile = blockIdx.x % 10;
  const int s    = blockIdx.x / 10;
  const int NS   = gridDim.x / 10;
  const int K1T[10] = {0, 0, 0, 0, 1, 1, 1, 2, 2, 3};
  const int K2T[10] = {0, 1, 2, 3, 1, 2, 3, 2, 3, 3};
  const int k1b = K1T[tile], k2b = K2T[tile];
  const int lane = tid & 63;
  const int w = tid >> 6;
  const int wm = (w >> 1) * 64;
  const int wn = (w & 1) * 64;
  const int l15 = lane & 15;
  const int quad = lane >> 4;

  const int NG = (T + 63) >> 6;           // 64-row groups
  const int GPB = (NG + NS - 1) / NS;
  const int g0 = s * GPB;
  const int gend = min(NG, g0 + GPB);

  f32x4 acc[4][4];
  #pragma unroll
  for (int i = 0; i < 4; ++i)
    #pragma unroll
    for (int j = 0; j < 4; ++j)
      acc[i][j] = (f32x4){0.f, 0.f, 0.f, 0.f};

  const int bsel = (k1b == k2b) ? 0 : 1;

  for (int g = g0; g < gend; ++g) {
    const int t0 = g << 6;
    #pragma unroll
    for (int it = 0; it < 4; ++it) {
      int lin = it * 256 + tid;
      int t = lin >> 4, c8 = lin & 15;
      int row = t0 + t;
      bf16x8 v;
      #pragma unroll
      for (int e = 0; e < 8; ++e) v[e] = (bf16)0.f;
      if (row < T)
        v = *reinterpret_cast<const bf16x8*>(A2 + (size_t)row * 512 + k1b * 128 + c8 * 8);
      int ts = t ^ ((c8 & 7) << 3);
      #pragma unroll
      for (int e = 0; e < 8; ++e) Ks[0][c8 * 8 + e][ts] = v[e];
    }
    if (bsel) {
      #pragma unroll
      for (int it = 0; it < 4; ++it) {
        int lin = it * 256 + tid;
        int t = lin >> 4, c8 = lin & 15;
        int row = t0 + t;
        bf16x8 v;
        #pragma unroll
        for (int e = 0; e < 8; ++e) v[e] = (bf16)0.f;
        if (row < T)
          v = *reinterpret_cast<const bf16x8*>(A2 + (size_t)row * 512 + k2b * 128 + c8 * 8);
        int ts = t ^ ((c8 & 7) << 3);
        #pragma unroll
        for (int e = 0; e < 8; ++e) Ks[1][c8 * 8 + e][ts] = v[e];
      }
    }
    __syncthreads();
    #pragma unroll
    for (int kk = 0; kk < 64; kk += 32) {
      bf16x8 af[4], bfv[4];
      #pragma unroll
      for (int i = 0; i < 4; ++i) {
        int r = wm + i * 16 + l15;
        int toff = (kk + quad * 8) ^ (((r >> 3) & 7) << 3);
        af[i] = *reinterpret_cast<const bf16x8*>(&Ks[0][r][toff]);
      }
      #pragma unroll
      for (int j = 0; j < 4; ++j) {
        int r = wn + j * 16 + l15;
        int toff = (kk + quad * 8) ^ (((r >> 3) & 7) << 3);
        bfv[j] = *reinterpret_cast<const bf16x8*>(&Ks[bsel][r][toff]);
      }
      #pragma unroll
      for (int i = 0; i < 4; ++i)
        #pragma unroll
        for (int j = 0; j < 4; ++j)
          acc[i][j] = __builtin_amdgcn_mfma_f32_16x16x32_bf16(af[i], bfv[j], acc[i][j], 0, 0, 0);
    }
    __syncthreads();
  }

  #pragma unroll
  for (int i = 0; i < 4; ++i) {
    #pragma unroll
    for (int r = 0; r < 4; ++r) {
      int grow = k1b * 128 + wm + i * 16 + quad * 4 + r;
      #pragma unroll
      for (int j = 0; j < 4; ++j) {
        int gcol = k2b * 128 + wn + j * 16 + l15;
        float v = acc[i][j][r];
        atomicAdd(&G[(size_t)grow * 512 + gcol], v);
        if (k1b != k2b)
          atomicAdd(&G[(size_t)gcol * 512 + grow], v);
      }
    }
  }
}

// A2 = bn_lrelu(hA) in-place, fused with column sums of A2 (csum, f32[512]).
__global__ __launch_bounds__(256) void act_colsum_k(bf16* __restrict__ hA,
    const float* __restrict__ scale, const float* __restrict__ shift,
    float* __restrict__ csum, int T) {
  __shared__ float sh[4 * 512];
  const int tid = threadIdx.x;
  const int c0 = (tid & 63) * 8;
  const int rofs = tid >> 6;
  float sc[8], sf[8];
  #pragma unroll
  for (int j = 0; j < 8; ++j) { sc[j] = scale[c0 + j]; sf[j] = shift[c0 + j]; }
  float acc[8];
  #pragma unroll
  for (int j = 0; j < 8; ++j) acc[j] = 0.f;
  for (int r = blockIdx.x * 4 + rofs; r < T; r += gridDim.x * 4) {
    bf16x8 v = *reinterpret_cast<const bf16x8*>(hA + (size_t)r * 512 + c0);
    bf16x8 o;
    #pragma unroll
    for (int j = 0; j < 8; ++j) {
      float f = sc[j] * (float)v[j] + sf[j];
      f = f >= 0.f ? f : 0.2f * f;
      o[j] = (bf16)f;
      acc[j] += (float)o[j];   // accumulate the bf16-rounded value GEMM2 will see
    }
    *reinterpret_cast<bf16x8*>(hA + (size_t)r * 512 + c0) = o;
  }
  #pragma unroll
  for (int j = 0; j < 8; ++j) sh[rofs * 512 + c0 + j] = acc[j];
  __syncthreads();
  for (int c = tid; c < 512; c += 256) {
    float s = sh[c] + sh[512 + c] + sh[1024 + c] + sh[1536 + c];
    atomicAdd(&csum[c], s);
  }
}

// Per output column c of GEMM2: sumB[c] = csum . W1b[:,c],
// sqB[c] = W1b[:,c]^T G W1b[:,c]. One block per 4 columns.
__global__ __launch_bounds__(256) void colstat_k(const float* __restrict__ G,
    const float* __restrict__ csum, const float* __restrict__ W1b,
    float* __restrict__ sumB, float* __restrict__ sqB) {
  __shared__ float wL[4][512];
  __shared__ float rq[4][4], rs[4][4];
  const int tid = threadIdx.x;
  const int c0 = blockIdx.x * 4;
  for (int idx = tid; idx < 2048; idx += 256) {
    int c = idx >> 9, k = idx & 511;
    wL[c][k] = W1b[(size_t)k * 1152 + c0 + c];
  }
  __syncthreads();
  float pq[4] = {0.f, 0.f, 0.f, 0.f};
  float ps[4] = {0.f, 0.f, 0.f, 0.f};
  for (int e = tid; e < 512 * 512; e += 256) {
    int i = e >> 9, j = e & 511;
    float g = G[e];
    #pragma unroll
    for (int c = 0; c < 4; ++c) pq[c] += g * wL[c][i] * wL[c][j];
  }
  for (int k = tid; k < 512; k += 256) {
    float cs = csum[k];
    #pragma unroll
    for (int c = 0; c < 4; ++c) ps[c] += cs * wL[c][k];
  }
  #pragma unroll
  for (int c = 0; c < 4; ++c) {
    #pragma unroll
    for (int off = 32; off > 0; off >>= 1) {
      pq[c] += __shfl_xor(pq[c], off);
      ps[c] += __shfl_xor(ps[c], off);
    }
  }
  const int w = tid >> 6, lane = tid & 63;
  if (lane == 0) {
    #pragma unroll
    for (int c = 0; c < 4; ++c) { rq[w][c] = pq[c]; rs[w][c] = ps[c]; }
  }
  __syncthreads();
  if (tid < 4) {
    sqB[c0 + tid]  = rq[0][tid] + rq[1][tid] + rq[2][tid] + rq[3][tid];
    sumB[c0 + tid] = rs[0][tid] + rs[1][tid] + rs[2][tid] + rs[3][tid];
  }
}

// transpose + fp32->bf16 convert: W (K,N) -> WT (N,K)
__global__ __launch_bounds__(256) void tconv_k(const float* __restrict__ W,
                                               bf16* __restrict__ WT, int K, int N) {
  int idx = blockIdx.x * 256 + threadIdx.x;
  if (idx < K * N) {
    int n = idx / K, k = idx - n * K;
    WT[(size_t)n * K + k] = (bf16)W[(size_t)k * N + n];
  }
}

__global__ __launch_bounds__(256) void bnfin_k(const float* __restrict__ sum,
    const float* __restrict__ sq, const float* __restrict__ g,
    const float* __restrict__ be, float* __restrict__ scale,
    float* __restrict__ shift, int C, float invR) {
  int c = blockIdx.x * 256 + threadIdx.x;
  if (c < C) {
    float m = sum[c] * invR;
    float v = sq[c] * invR - m * m;
    float a = g[c] * rsqrtf(v + 1e-5f);
    scale[c] = a;
    shift[c] = be[c] - m * a;
  }
}

__global__ __launch_bounds__(256) void cntint_k(const int* __restrict__ edges,
                                                int* __restrict__ cnt, int T) {
  int t = blockIdx.x * 256 + threadIdx.x;
  if (t < T) {
    atomicAdd(&cnt[edges[2 * t]], 1);
    atomicAdd(&cnt[edges[2 * t + 1]], 1);
  }
}

__global__ __launch_bounds__(256) void invcnt_k(const int* __restrict__ cnt,
                                                float* __restrict__ invc, int O) {
  int i = blockIdx.x * 256 + threadIdx.x;
  if (i < O) {
    float c = fminf(fmaxf((float)cnt[i], 1.f), (float)O);
    invc[i] = 1.f / c;
  }
}

// single-block exclusive scan of cnt -> rowptr, head
__global__ __launch_bounds__(1024) void scan_k(const int* __restrict__ cnt,
    int* __restrict__ rowptr, int* __restrict__ head, int O, int total) {
  __shared__ int sh[1024];
  const int t = threadIdx.x;
  const int C = (O + 1023) / 1024;
  const int i0 = t * C;
  int s = 0;
  for (int i = 0; i < C; ++i) { int idx = i0 + i; if (idx < O) s += cnt[idx]; }
  sh[t] = s;
  __syncthreads();
  for (int d = 1; d < 1024; d <<= 1) {
    int v = (t >= d) ? sh[t - d] : 0;
    __syncthreads();
    sh[t] += v;
    __syncthreads();
  }
  int run = (t == 0) ? 0 : sh[t - 1];
  for (int i = 0; i < C; ++i) {
    int idx = i0 + i;
    if (idx < O) { rowptr[idx] = run; head[idx] = run; run += cnt[idx]; }
  }
  if (t == 0) rowptr[O] = total;
}

// role-tagged incidence list: entry = (t<<1)|role, role 0 = subject, 1 = object
__global__ __launch_bounds__(256) void fill_k(const int* __restrict__ edges,
    int* __restrict__ head, int* __restrict__ list, int T) {
  int t = blockIdx.x * 256 + threadIdx.x;
  if (t < T) {
    int s = edges[2 * t];
    int p = atomicAdd(&head[s], 1);
    list[p] = t << 1;
    int o = edges[2 * t + 1];
    p = atomicAdd(&head[o], 1);
    list[p] = (t << 1) | 1;
  }
}

__global__ __launch_bounds__(256) void final_k(float* __restrict__ buf,
    const float* __restrict__ scale, const float* __restrict__ shift, int n) {
  int i = blockIdx.x * 256 + threadIdx.x;
  if (i < n) {
    int c = i & 127;
    float v = scale[c] * buf[i] + shift[c];
    buf[i] = v >= 0.f ? v : 0.2f * v;
  }
}

extern "C" void kernel_launch(void* const* d_in, const int* in_sizes, int n_in,
                              void* d_out, int out_size, void* d_ws, size_t ws_size,
                              hipStream_t stream) {
  const float* obj   = (const float*)d_in[0];
  const float* pred  = (const float*)d_in[1];
  const int*   edges = (const int*)d_in[2];
  const float* W1a = (const float*)d_in[3];
  const float* g1a = (const float*)d_in[5];
  const float* be1a= (const float*)d_in[6];
  const float* W1b = (const float*)d_in[7];
  const float* g1b = (const float*)d_in[9];
  const float* be1b= (const float*)d_in[10];
  const float* W2a = (const float*)d_in[11];
  const float* g2a = (const float*)d_in[13];
  const float* be2a= (const float*)d_in[14];
  const float* W2b = (const float*)d_in[15];
  const float* g2b = (const float*)d_in[17];
  const float* be2b= (const float*)d_in[18];

  const int O = in_sizes[0] / 128;
  const int T = in_sizes[1] / 128;
  float* out_obj = (float*)d_out;
  float* out_p   = (float*)d_out + (size_t)O * 128;

  char* base = (char*)d_ws;
  size_t off = 0;
  auto alloc = [&](size_t bytes) { size_t p = off; off += (bytes + 255) & ~(size_t)255; return p; };
  size_t oWT1a = alloc((size_t)384 * 512 * 2);
  size_t oWT1b = alloc((size_t)512 * 1152 * 2);
  size_t oWT2a = alloc((size_t)512 * 512 * 2);
  size_t oWT2b = alloc((size_t)512 * 128 * 2);
  size_t oSums = alloc(4608 * 4);
  size_t oScl  = alloc(4608 * 4);
  size_t oG    = alloc((size_t)512 * 512 * 4);
  size_t oCsum = alloc(512 * 4);
  size_t oCnt  = alloc((size_t)O * 4);
  size_t oInvc = alloc((size_t)O * 4);
  size_t oRp   = alloc((size_t)(O + 1) * 4);
  size_t oHead = alloc((size_t)O * 4);
  size_t oList = alloc((size_t)2 * T * 4);
  size_t oHA   = alloc((size_t)T * 512 * 2);    // hA/A2 bf16; h2 aliases later
  size_t oPool = off;                           // pooledF f32 (O,512)
  size_t oBuf  = oPool + (((size_t)O * 512 * 4 + 255) & ~(size_t)255);

  // chunk buffer: rows of 1024 bf16 ([s 512 | o 512])
  int chunkT = 0;
  if (ws_size > oBuf) {
    size_t ct = (ws_size - oBuf) / 2048;
    if (ct > (size_t)T) ct = T;
    chunkT = (int)(ct & ~(size_t)127);
  }
  const bool chunked = (chunkT >= 8192);

  bf16* WT1a = (bf16*)(base + oWT1a);
  bf16* WT1b = (bf16*)(base + oWT1b);
  bf16* WT2a = (bf16*)(base + oWT2a);
  bf16* WT2b = (bf16*)(base + oWT2b);
  float* sums = (float*)(base + oSums);
  float* sumA = sums,        * sqA = sums + 512;
  float* sumB = sums + 1024, * sqB = sums + 2176;
  float* sumC = sums + 3328, * sqC = sums + 3840;
  float* sumD = sums + 4352, * sqD = sums + 4480;
  float* scl = (float*)(base + oScl);
  float* scaleA = scl,        * shiftA = scl + 512;
  float* scaleB = scl + 1024, * shiftB = scl + 2176;
  float* scaleC = scl + 3328, * shiftC = scl + 3840;
  float* scaleD = scl + 4352, * shiftD = scl + 4480;
  float* Gm   = (float*)(base + oG);
  float* csum = (float*)(base + oCsum);
  int*   cntI = (int*)(base + oCnt);
  float* invc = (float*)(base + oInvc);
  int*   rowptr = (int*)(base + oRp);
  int*   head = (int*)(base + oHead);
  int*   list = (int*)(base + oList);
  bf16*  hA = (bf16*)(base + oHA);     // also A2 (in-place), later h2
  bf16*  h2 = (bf16*)(base + oHA);
  float* pooledF = (float*)(base + oPool);
  bf16*  buf = (bf16*)(base + oBuf);
  float* objpre = out_obj;

  hipMemsetAsync(sums, 0, 4608 * 4, stream);
  hipMemsetAsync(cntI, 0, (size_t)O * 4, stream);
  hipMemsetAsync(Gm, 0, (size_t)512 * 512 * 4, stream);
  hipMemsetAsync(csum, 0, 512 * 4, stream);
  hipMemsetAsync(pooledF, 0, (size_t)O * 512 * 4, stream);

  tconv_k<<<(384 * 512 + 255) / 256, 256, 0, stream>>>(W1a, WT1a, 384, 512);
  tconv_k<<<(512 * 1152 + 255) / 256, 256, 0, stream>>>(W1b, WT1b, 512, 1152);
  tconv_k<<<(512 * 512 + 255) / 256, 256, 0, stream>>>(W2a, WT2a, 512, 512);
  tconv_k<<<(512 * 128 + 255) / 256, 256, 0, stream>>>(W2b, WT2b, 512, 128);
  cntint_k<<<(T + 255) / 256, 256, 0, stream>>>(edges, cntI, T);
  invcnt_k<<<(O + 255) / 256, 256, 0, stream>>>(cntI, invc, O);
  if (chunked) {
    scan_k<<<1, 1024, 0, stream>>>(cntI, rowptr, head, O, 2 * T);
    fill_k<<<(T + 255) / 256, 256, 0, stream>>>(edges, head, list, T);
  }

  const int Tb = (T + BM - 1) / BM;
  const int Ob = (O + BM - 1) / BM;

  // GEMM1: gathered (T,384) @ W1a -> hA raw bf16 + statsA
  {
    dim3 g(512 / BN, Tb);
    gemm_k<0, 0><<<g, 256, 0, stream>>>(nullptr, nullptr, obj, pred, edges, nullptr,
        nullptr, nullptr, nullptr, nullptr, WT1a, hA, nullptr, nullptr, sumA, sqA,
        T, 512, 384, 0);
  }
  bnfin_k<<<2, 256, 0, stream>>>(sumA, sqA, g1a, be1a, scaleA, shiftA, 512, 1.f / T);

  // A2 = bn_lrelu(hA) in-place + column sums
  act_colsum_k<<<1024, 256, 0, stream>>>(hA, scaleA, shiftA, csum, T);
  // G = A2^T A2; then GEMM2 output stats algebraically
  gram_k<<<10 * 48, 256, 0, stream>>>(hA, Gm, T);
  colstat_k<<<288, 256, 0, stream>>>(Gm, csum, W1b, sumB, sqB);
  bnfin_k<<<5, 256, 0, stream>>>(sumB, sqB, g1b, be1b, scaleB, shiftB, 1152, 1.f / T);

  if (chunked) {
    // natural-order chunked GEMM2 with fused bn_lrelu; dense buf; CSR pooling
    for (int c0 = 0; c0 < T; c0 += chunkT) {
      int c1 = min(T, c0 + chunkT);
      dim3 g(1152 / BN, (c1 - c0 + BM - 1) / BM);
      gemm_k<3, 5><<<g, 256, 0, stream>>>(hA, nullptr, nullptr, nullptr, nullptr,
          nullptr, nullptr, nullptr, scaleB, shiftB, WT1b, buf, out_p, nullptr,
          nullptr, nullptr, c1, 1152, 512, c0);
      gatherc_k<<<(O + 3) / 4, 256, 0, stream>>>(buf, rowptr, list, pooledF, c0, c1, O);
    }
  } else {
    // tier-3: single GEMM2 pass with atomic scatter
    dim3 g(1152 / BN, Tb);
    gemm_k<3, 2><<<g, 256, 0, stream>>>(hA, nullptr, nullptr, nullptr, edges, nullptr,
        nullptr, nullptr, scaleB, shiftB, WT1b, nullptr, out_p, pooledF, nullptr,
        nullptr, T, 1152, 512, 0);
  }

  // GEMM3: (pooledF * invc) (O,512) @ W2a -> h2 bf16 + statsC
  {
    dim3 g(512 / BN, Ob);
    gemm_k<2, 0><<<g, 256, 0, stream>>>(nullptr, pooledF, nullptr, nullptr, nullptr,
        invc, nullptr, nullptr, nullptr, nullptr, WT2a, h2, nullptr, nullptr,
        sumC, sqC, O, 512, 512, 0);
  }
  bnfin_k<<<2, 256, 0, stream>>>(sumC, sqC, g2a, be2a, scaleC, shiftC, 512, 1.f / O);

  // GEMM4: bn_lrelu(h2) (O,512) @ W2b -> objpre f32 (in d_out) + statsD
  {
    dim3 g(128 / BN, Ob);
    gemm_k<1, 3><<<g, 256, 0, stream>>>(h2, nullptr, nullptr, nullptr, nullptr, nullptr,
        scaleC, shiftC, nullptr, nullptr, WT2b, nullptr, objpre, nullptr, sumD, sqD,
        O, 128, 512, 0);
  }
  bnfin_k<<<1, 256, 0, stream>>>(sumD, sqD, g2b, be2b, scaleD, shiftD, 128, 1.f / O);

  final_k<<<((size_t)O * 128 + 255) / 256, 256, 0, stream>>>(objpre, scaleD, shiftD,
      (int)((size_t)O * 128));
}

// Round 4
// 2028.203 us; speedup vs baseline: 1.1169x; 1.0974x over previous
//
#include <hip/hip_runtime.h>

typedef __bf16 bf16;
typedef __bf16 bf16x4 __attribute__((ext_vector_type(4)));
typedef __bf16 bf16x8 __attribute__((ext_vector_type(8)));
typedef float  f32x4  __attribute__((ext_vector_type(4)));

#define BM 128
#define BN 128
#define BKT 64
#define LDT 72   // gram LDS row stride (t-dim padded)

#ifndef __has_builtin
#define __has_builtin(x) 0
#endif

// 16B direct global->LDS: wave-uniform LDS base, per-lane global src (lane*16B dest).
// Fallback produces the identical layout via per-lane VGPR copy.
#if __has_builtin(__builtin_amdgcn_global_load_lds)
#define GLL16(srcp, basep) \
  __builtin_amdgcn_global_load_lds( \
      (const __attribute__((address_space(1))) unsigned int*)(srcp), \
      (__attribute__((address_space(3))) unsigned int*)(basep), 16, 0, 0)
#else
#define GLL16(srcp, basep) \
  (((bf16x8*)(basep))[lane] = *(const bf16x8*)(srcp))
#endif

// AMODE: 0 = gather concat [obj[s] | pred | obj[o]] (f32 -> bf16)
//        1 = bn_lrelu(scale*x+shift) applied to bf16 source
//        2 = f32 source * invcnt[row]
//        3 = plain bf16 copy (global_load_lds path)
// EPI:   0 = store bf16 + column stats atomics
//        2 = bn_lrelu(out-col scale/shift) then atomic scatter (tier-3 fallback)
//        3 = store f32 + column stats atomics
//        5 = bn_lrelu(out-col scale/shift); cols<512 -> buf[(row-rbase)*1024 + n1] bf16,
//            512..639 -> outF[row*128+..] (new_p f32), >=640 -> buf[.. + n1-128] bf16
// LDS layout: linear [128][64] bf16, 16B chunks XOR-swizzled by (row&7) on the
// SOURCE side (global addr pre-swizzle for GLL, swizzled write for VGPR paths);
// fragment reads apply the same XOR -> 2-way bank aliasing only.
template<int AMODE, int EPI>
__global__ __launch_bounds__(256) void gemm_k(
    const bf16* __restrict__ Abf, const float* __restrict__ Af32,
    const float* __restrict__ obj, const float* __restrict__ pred,
    const int* __restrict__ edges, const float* __restrict__ invcnt,
    const float* __restrict__ scale, const float* __restrict__ shift,   // input-col bn (AMODE==1)
    const float* __restrict__ oscale, const float* __restrict__ oshift, // output-col bn (EPI==2/5)
    const bf16* __restrict__ WT,      // (N,K) bf16, pre-transposed
    bf16* __restrict__ outB, float* __restrict__ outF,
    float* __restrict__ pooled, float* __restrict__ gsum, float* __restrict__ gsq,
    int M, int N, int K, int rbase)
{
  __shared__ __align__(16) bf16 As[BM * 64];
  __shared__ __align__(16) bf16 Bs[BN * 64];
  __shared__ float sc_sh[(AMODE == 1) ? 512 : 1];
  __shared__ float sh_sh[(AMODE == 1) ? 512 : 1];
  __shared__ float osc[(EPI == 2 || EPI == 5) ? BN : 1];
  __shared__ float osh[(EPI == 2 || EPI == 5) ? BN : 1];
  __shared__ int eS[(AMODE == 0 || EPI == 2) ? BM : 1];
  __shared__ int eO[(AMODE == 0 || EPI == 2) ? BM : 1];

  const int tid = threadIdx.x;

  // ---- XCD-aligned swizzle (bijective; tail handled linearly)
  int bx = blockIdx.x, by = blockIdx.y;
  {
    const int NX = gridDim.x, NY = gridDim.y;
    int L = by * NX + bx;
    int bpg = NX * 8;
    int nFull = NY >> 3;
    int Lfull = nFull * bpg;
    if (L < Lfull) {
      int g = L / bpg, w2 = L - g * bpg;
      by = (g << 3) + (w2 & 7);
      bx = w2 >> 3;
    } else {
      int r2 = L - Lfull;
      int q = r2 / NX;
      by = (nFull << 3) + q;
      bx = r2 - q * NX;
    }
  }
  const int m0 = rbase + by * BM;
  const int n0 = bx * BN;

  const int lane = tid & 63;
  const int w = tid >> 6;
  const int wm = (w >> 1) * 64;
  const int wn = (w & 1) * 64;
  const int l15 = lane & 15;
  const int quad = lane >> 4;

  if (AMODE == 1) {
    for (int c = tid; c < K; c += 256) { sc_sh[c] = scale[c]; sh_sh[c] = shift[c]; }
  }
  if (EPI == 2 || EPI == 5) {
    if (tid < BN) { osc[tid] = oscale[n0 + tid]; osh[tid] = oshift[n0 + tid]; }
  }
  if (AMODE == 0 || EPI == 2) {
    if (tid < BM) {
      int r = m0 + tid; if (r >= M) r = M - 1;
      eS[tid] = edges[2 * r];
      eO[tid] = edges[2 * r + 1];
    }
  }
  __syncthreads();

  f32x4 acc[4][4];
  #pragma unroll
  for (int i = 0; i < 4; ++i)
    #pragma unroll
    for (int j = 0; j < 4; ++j)
      acc[i][j] = (f32x4){0.f, 0.f, 0.f, 0.f};

  const int rsub = lane >> 3;   // 0..7: row within 8-row block
  const int cch  = lane & 7;    // 16B chunk within row

  for (int k0 = 0; k0 < K; k0 += BKT) {
    // ---- stage B^T tile: 128 rows x 64 k, direct-to-LDS, source-swizzled
    #pragma unroll
    for (int it = 0; it < 4; ++it) {
      int blk = it * 4 + w;
      int r = blk * 8 + rsub;
      int cs = cch ^ (r & 7);
      const bf16* src = WT + (size_t)(n0 + r) * K + k0 + cs * 8;
      GLL16(src, &Bs[blk * 512]);
    }
    // ---- stage A tile
    if (AMODE == 3) {
      #pragma unroll
      for (int it = 0; it < 4; ++it) {
        int blk = it * 4 + w;
        int r = blk * 8 + rsub;
        int row = m0 + r; if (row >= M) row = M - 1;
        int cs = cch ^ (r & 7);
        const bf16* src = Abf + (size_t)row * K + k0 + cs * 8;
        GLL16(src, &As[blk * 512]);
      }
    } else if (AMODE == 1) {
      int idx = tid;
      #pragma unroll
      for (int it = 0; it < 4; ++it, idx += 256) {
        int r = idx >> 3, ch = idx & 7;
        int row = m0 + r; if (row >= M) row = M - 1;
        bf16x8 v = *reinterpret_cast<const bf16x8*>(Abf + (size_t)row * K + k0 + ch * 8);
        bf16x8 o;
        #pragma unroll
        for (int e = 0; e < 8; ++e) {
          int c = k0 + ch * 8 + e;
          float f = sc_sh[c] * (float)v[e] + sh_sh[c];
          f = f >= 0.f ? f : 0.2f * f;
          o[e] = (bf16)f;
        }
        *reinterpret_cast<bf16x8*>(&As[r * 64 + ((ch ^ (r & 7)) << 3)]) = o;
      }
    } else {
      int idx = tid;
      #pragma unroll
      for (int it = 0; it < 8; ++it, idx += 256) {
        int r = idx >> 4, c4 = (idx & 15) << 2;   // element offset, multiple of 4
        int row = m0 + r; if (row >= M) row = M - 1;
        const float* src;
        float mul = 1.f;
        if (AMODE == 0) {
          int k = k0 + c4;
          if (k < 128)      src = obj  + (size_t)eS[r] * 128 + k;
          else if (k < 256) src = pred + (size_t)row * 128 + (k - 128);
          else              src = obj  + (size_t)eO[r] * 128 + (k - 256);
        } else {
          src = Af32 + (size_t)row * K + k0 + c4;
          mul = invcnt[row];
        }
        float4 v = *reinterpret_cast<const float4*>(src);
        bf16x4 o;
        o[0] = (bf16)(v.x * mul); o[1] = (bf16)(v.y * mul);
        o[2] = (bf16)(v.z * mul); o[3] = (bf16)(v.w * mul);
        int ch = c4 >> 3;                 // 16B chunk
        int half = (c4 >> 2) & 1;         // which 8B half
        *reinterpret_cast<bf16x4*>(&As[r * 64 + ((ch ^ (r & 7)) << 3) + (half << 2)]) = o;
      }
    }
    __syncthreads();
    #pragma unroll
    for (int kk = 0; kk < BKT; kk += 32) {
      bf16x8 af[4], bfv[4];
      #pragma unroll
      for (int i = 0; i < 4; ++i) {
        int r = wm + i * 16 + l15;
        int ci = (kk >> 3) + quad;
        af[i] = *reinterpret_cast<const bf16x8*>(&As[r * 64 + ((ci ^ (r & 7)) << 3)]);
      }
      #pragma unroll
      for (int j = 0; j < 4; ++j) {
        int r = wn + j * 16 + l15;
        int ci = (kk >> 3) + quad;
        bfv[j] = *reinterpret_cast<const bf16x8*>(&Bs[r * 64 + ((ci ^ (r & 7)) << 3)]);
      }
      #pragma unroll
      for (int i = 0; i < 4; ++i)
        #pragma unroll
        for (int j = 0; j < 4; ++j)
          acc[i][j] = __builtin_amdgcn_mfma_f32_16x16x32_bf16(af[i], bfv[j], acc[i][j], 0, 0, 0);
    }
    __syncthreads();
  }

  if (EPI == 2) {
    #pragma unroll
    for (int i = 0; i < 4; ++i) {
      #pragma unroll
      for (int r = 0; r < 4; ++r) {
        int lrow = wm + i * 16 + quad * 4 + r;
        int row = m0 + lrow;
        if (row >= M) continue;
        #pragma unroll
        for (int j = 0; j < 4; ++j) {
          int cl = wn + j * 16 + l15;
          int n1 = n0 + cl;
          float v = osc[cl] * acc[i][j][r] + osh[cl];
          v = v >= 0.f ? v : 0.2f * v;
          if (n1 < 512)      atomicAdd(&pooled[(size_t)eS[lrow] * 512 + n1], v);
          else if (n1 < 640) outF[(size_t)row * 128 + (n1 - 512)] = v;
          else               atomicAdd(&pooled[(size_t)eO[lrow] * 512 + (n1 - 640)], v);
        }
      }
    }
  } else if (EPI == 5) {
    #pragma unroll
    for (int i = 0; i < 4; ++i) {
      #pragma unroll
      for (int r = 0; r < 4; ++r) {
        int lrow = wm + i * 16 + quad * 4 + r;
        int row = m0 + lrow;
        if (row >= M) continue;
        #pragma unroll
        for (int j = 0; j < 4; ++j) {
          int cl = wn + j * 16 + l15;
          int n1 = n0 + cl;
          float v = osc[cl] * acc[i][j][r] + osh[cl];
          v = v >= 0.f ? v : 0.2f * v;
          if (n1 < 512)      outB[(size_t)(row - rbase) * 1024 + n1] = (bf16)v;
          else if (n1 < 640) outF[(size_t)row * 128 + (n1 - 512)] = v;
          else               outB[(size_t)(row - rbase) * 1024 + (n1 - 128)] = (bf16)v;
        }
      }
    }
  } else {
    #pragma unroll
    for (int j = 0; j < 4; ++j) {
      float s = 0.f, q = 0.f;
      #pragma unroll
      for (int i = 0; i < 4; ++i) {
        #pragma unroll
        for (int r = 0; r < 4; ++r) {
          int row = m0 + wm + i * 16 + quad * 4 + r;
          if (row >= M) continue;
          float v = acc[i][j][r];
          s += v; q += v * v;
          int col = n0 + wn + j * 16 + l15;
          if (EPI == 0) outB[(size_t)row * N + col] = (bf16)v;
          if (EPI == 3) outF[(size_t)row * N + col] = v;
        }
      }
      s += __shfl_xor(s, 16); q += __shfl_xor(q, 16);
      s += __shfl_xor(s, 32); q += __shfl_xor(q, 32);
      if (quad == 0) {
        int col = n0 + wn + j * 16 + l15;
        atomicAdd(&gsum[col], s);
        atomicAdd(&gsq[col], q);
      }
    }
  }
}

// Chunked CSR pooling: one wave per object scans its role-tagged edge list,
// accumulates rows with t in [c0,c1) from the dense chunk buffer
// (row layout: [s-part 512 | o-part 512] bf16), then non-atomic += into pooled.
__global__ __launch_bounds__(256) void gatherc_k(const bf16* __restrict__ buf,
    const int* __restrict__ rowptr, const int* __restrict__ list,
    float* __restrict__ pooled, int c0, int c1, int O) {
  int o = blockIdx.x * 4 + (threadIdx.x >> 6);
  if (o >= O) return;
  int lane = threadIdx.x & 63;
  int cc = lane * 8;
  int e0 = rowptr[o], e1 = rowptr[o + 1];
  float acc[8];
  #pragma unroll
  for (int j = 0; j < 8; ++j) acc[j] = 0.f;
  bool any = false;
  for (int e = e0; e < e1; ++e) {
    int id = list[e];
    int t = id >> 1;
    if (t < c0 || t >= c1) continue;
    const bf16* row = buf + (size_t)(t - c0) * 1024 + (id & 1) * 512 + cc;
    bf16x8 v = *reinterpret_cast<const bf16x8*>(row);
    #pragma unroll
    for (int j = 0; j < 8; ++j) acc[j] += (float)v[j];
    any = true;
  }
  if (!any) return;
  float* dst = pooled + (size_t)o * 512 + cc;
  float4 a = *reinterpret_cast<float4*>(dst);
  float4 b = *reinterpret_cast<float4*>(dst + 4);
  a.x += acc[0]; a.y += acc[1]; a.z += acc[2]; a.w += acc[3];
  b.x += acc[4]; b.y += acc[5]; b.z += acc[6]; b.w += acc[7];
  *reinterpret_cast<float4*>(dst) = a;
  *reinterpret_cast<float4*>(dst + 4) = b;
}

// Gram matrix G = A2^T A2 (512x512 f32) over T rows. Upper-triangle tile pairs only
// (10 of 16); off-diagonal tiles mirror their result at write time. Split-K over T.
__global__ __launch_bounds__(256) void gram_k(const bf16* __restrict__ A2,
                                              float* __restrict__ G, int T) {
  __shared__ __align__(16) bf16 Ks[2][128][LDT];
  const int tid = threadIdx.x;
  const int tile = blockIdx.x % 10;
  const int s    = blockIdx.x / 10;
  const int NS   = gridDim.x / 10;
  const int K1T[10] = {0, 0, 0, 0, 1, 1, 1, 2, 2, 3};
  const int K2T[10] = {0, 1, 2, 3, 1, 2, 3, 2, 3, 3};
  const int k1b = K1T[tile], k2b = K2T[tile];
  const int lane = tid & 63;
  const int w = tid >> 6;
  const int wm = (w >> 1) * 64;
  const int wn = (w & 1) * 64;
  const int l15 = lane & 15;
  const int quad = lane >> 4;

  const int NG = (T + 63) >> 6;           // 64-row groups
  const int GPB = (NG + NS - 1) / NS;
  const int g0 = s * GPB;
  const int gend = min(NG, g0 + GPB);

  f32x4 acc[4][4];
  #pragma unroll
  for (int i = 0; i < 4; ++i)
    #pragma unroll
    for (int j = 0; j < 4; ++j)
      acc[i][j] = (f32x4){0.f, 0.f, 0.f, 0.f};

  const int bsel = (k1b == k2b) ? 0 : 1;

  for (int g = g0; g < gend; ++g) {
    const int t0 = g << 6;
    #pragma unroll
    for (int it = 0; it < 4; ++it) {
      int lin = it * 256 + tid;
      int t = lin >> 4, c8 = lin & 15;
      int row = t0 + t;
      bf16x8 v;
      #pragma unroll
      for (int e = 0; e < 8; ++e) v[e] = (bf16)0.f;
      if (row < T)
        v = *reinterpret_cast<const bf16x8*>(A2 + (size_t)row * 512 + k1b * 128 + c8 * 8);
      int ts = t ^ ((c8 & 7) << 3);
      #pragma unroll
      for (int e = 0; e < 8; ++e) Ks[0][c8 * 8 + e][ts] = v[e];
    }
    if (bsel) {
      #pragma unroll
      for (int it = 0; it < 4; ++it) {
        int lin = it * 256 + tid;
        int t = lin >> 4, c8 = lin & 15;
        int row = t0 + t;
        bf16x8 v;
        #pragma unroll
        for (int e = 0; e < 8; ++e) v[e] = (bf16)0.f;
        if (row < T)
          v = *reinterpret_cast<const bf16x8*>(A2 + (size_t)row * 512 + k2b * 128 + c8 * 8);
        int ts = t ^ ((c8 & 7) << 3);
        #pragma unroll
        for (int e = 0; e < 8; ++e) Ks[1][c8 * 8 + e][ts] = v[e];
      }
    }
    __syncthreads();
    #pragma unroll
    for (int kk = 0; kk < 64; kk += 32) {
      bf16x8 af[4], bfv[4];
      #pragma unroll
      for (int i = 0; i < 4; ++i) {
        int r = wm + i * 16 + l15;
        int toff = (kk + quad * 8) ^ (((r >> 3) & 7) << 3);
        af[i] = *reinterpret_cast<const bf16x8*>(&Ks[0][r][toff]);
      }
      #pragma unroll
      for (int j = 0; j < 4; ++j) {
        int r = wn + j * 16 + l15;
        int toff = (kk + quad * 8) ^ (((r >> 3) & 7) << 3);
        bfv[j] = *reinterpret_cast<const bf16x8*>(&Ks[bsel][r][toff]);
      }
      #pragma unroll
      for (int i = 0; i < 4; ++i)
        #pragma unroll
        for (int j = 0; j < 4; ++j)
          acc[i][j] = __builtin_amdgcn_mfma_f32_16x16x32_bf16(af[i], bfv[j], acc[i][j], 0, 0, 0);
    }
    __syncthreads();
  }

  #pragma unroll
  for (int i = 0; i < 4; ++i) {
    #pragma unroll
    for (int r = 0; r < 4; ++r) {
      int grow = k1b * 128 + wm + i * 16 + quad * 4 + r;
      #pragma unroll
      for (int j = 0; j < 4; ++j) {
        int gcol = k2b * 128 + wn + j * 16 + l15;
        float v = acc[i][j][r];
        atomicAdd(&G[(size_t)grow * 512 + gcol], v);
        if (k1b != k2b)
          atomicAdd(&G[(size_t)gcol * 512 + grow], v);
      }
    }
  }
}

// A2 = bn_lrelu(hA) in-place, fused with column sums of A2 (csum, f32[512]).
__global__ __launch_bounds__(256) void act_colsum_k(bf16* __restrict__ hA,
    const float* __restrict__ scale, const float* __restrict__ shift,
    float* __restrict__ csum, int T) {
  __shared__ float sh[4 * 512];
  const int tid = threadIdx.x;
  const int c0 = (tid & 63) * 8;
  const int rofs = tid >> 6;
  float sc[8], sf[8];
  #pragma unroll
  for (int j = 0; j < 8; ++j) { sc[j] = scale[c0 + j]; sf[j] = shift[c0 + j]; }
  float acc[8];
  #pragma unroll
  for (int j = 0; j < 8; ++j) acc[j] = 0.f;
  for (int r = blockIdx.x * 4 + rofs; r < T; r += gridDim.x * 4) {
    bf16x8 v = *reinterpret_cast<const bf16x8*>(hA + (size_t)r * 512 + c0);
    bf16x8 o;
    #pragma unroll
    for (int j = 0; j < 8; ++j) {
      float f = sc[j] * (float)v[j] + sf[j];
      f = f >= 0.f ? f : 0.2f * f;
      o[j] = (bf16)f;
      acc[j] += (float)o[j];   // accumulate the bf16-rounded value GEMM2 will see
    }
    *reinterpret_cast<bf16x8*>(hA + (size_t)r * 512 + c0) = o;
  }
  #pragma unroll
  for (int j = 0; j < 8; ++j) sh[rofs * 512 + c0 + j] = acc[j];
  __syncthreads();
  for (int c = tid; c < 512; c += 256) {
    float s = sh[c] + sh[512 + c] + sh[1024 + c] + sh[1536 + c];
    atomicAdd(&csum[c], s);
  }
}

// Per output column c of GEMM2: sumB[c] = csum . W1b[:,c],
// sqB[c] = W1b[:,c]^T G W1b[:,c]. One block per 4 columns.
__global__ __launch_bounds__(256) void colstat_k(const float* __restrict__ G,
    const float* __restrict__ csum, const float* __restrict__ W1b,
    float* __restrict__ sumB, float* __restrict__ sqB) {
  __shared__ float wL[4][512];
  __shared__ float rq[4][4], rs[4][4];
  const int tid = threadIdx.x;
  const int c0 = blockIdx.x * 4;
  for (int idx = tid; idx < 2048; idx += 256) {
    int c = idx >> 9, k = idx & 511;
    wL[c][k] = W1b[(size_t)k * 1152 + c0 + c];
  }
  __syncthreads();
  float pq[4] = {0.f, 0.f, 0.f, 0.f};
  float ps[4] = {0.f, 0.f, 0.f, 0.f};
  for (int e = tid; e < 512 * 512; e += 256) {
    int i = e >> 9, j = e & 511;
    float g = G[e];
    #pragma unroll
    for (int c = 0; c < 4; ++c) pq[c] += g * wL[c][i] * wL[c][j];
  }
  for (int k = tid; k < 512; k += 256) {
    float cs = csum[k];
    #pragma unroll
    for (int c = 0; c < 4; ++c) ps[c] += cs * wL[c][k];
  }
  #pragma unroll
  for (int c = 0; c < 4; ++c) {
    #pragma unroll
    for (int off = 32; off > 0; off >>= 1) {
      pq[c] += __shfl_xor(pq[c], off);
      ps[c] += __shfl_xor(ps[c], off);
    }
  }
  const int w = tid >> 6, lane = tid & 63;
  if (lane == 0) {
    #pragma unroll
    for (int c = 0; c < 4; ++c) { rq[w][c] = pq[c]; rs[w][c] = ps[c]; }
  }
  __syncthreads();
  if (tid < 4) {
    sqB[c0 + tid]  = rq[0][tid] + rq[1][tid] + rq[2][tid] + rq[3][tid];
    sumB[c0 + tid] = rs[0][tid] + rs[1][tid] + rs[2][tid] + rs[3][tid];
  }
}

// transpose + fp32->bf16 convert: W (K,N) -> WT (N,K)
__global__ __launch_bounds__(256) void tconv_k(const float* __restrict__ W,
                                               bf16* __restrict__ WT, int K, int N) {
  int idx = blockIdx.x * 256 + threadIdx.x;
  if (idx < K * N) {
    int n = idx / K, k = idx - n * K;
    WT[(size_t)n * K + k] = (bf16)W[(size_t)k * N + n];
  }
}

__global__ __launch_bounds__(256) void bnfin_k(const float* __restrict__ sum,
    const float* __restrict__ sq, const float* __restrict__ g,
    const float* __restrict__ be, float* __restrict__ scale,
    float* __restrict__ shift, int C, float invR) {
  int c = blockIdx.x * 256 + threadIdx.x;
  if (c < C) {
    float m = sum[c] * invR;
    float v = sq[c] * invR - m * m;
    float a = g[c] * rsqrtf(v + 1e-5f);
    scale[c] = a;
    shift[c] = be[c] - m * a;
  }
}

__global__ __launch_bounds__(256) void cntint_k(const int* __restrict__ edges,
                                                int* __restrict__ cnt, int T) {
  int t = blockIdx.x * 256 + threadIdx.x;
  if (t < T) {
    atomicAdd(&cnt[edges[2 * t]], 1);
    atomicAdd(&cnt[edges[2 * t + 1]], 1);
  }
}

__global__ __launch_bounds__(256) void invcnt_k(const int* __restrict__ cnt,
                                                float* __restrict__ invc, int O) {
  int i = blockIdx.x * 256 + threadIdx.x;
  if (i < O) {
    float c = fminf(fmaxf((float)cnt[i], 1.f), (float)O);
    invc[i] = 1.f / c;
  }
}

// single-block exclusive scan of cnt -> rowptr, head
__global__ __launch_bounds__(1024) void scan_k(const int* __restrict__ cnt,
    int* __restrict__ rowptr, int* __restrict__ head, int O, int total) {
  __shared__ int sh[1024];
  const int t = threadIdx.x;
  const int C = (O + 1023) / 1024;
  const int i0 = t * C;
  int s = 0;
  for (int i = 0; i < C; ++i) { int idx = i0 + i; if (idx < O) s += cnt[idx]; }
  sh[t] = s;
  __syncthreads();
  for (int d = 1; d < 1024; d <<= 1) {
    int v = (t >= d) ? sh[t - d] : 0;
    __syncthreads();
    sh[t] += v;
    __syncthreads();
  }
  int run = (t == 0) ? 0 : sh[t - 1];
  for (int i = 0; i < C; ++i) {
    int idx = i0 + i;
    if (idx < O) { rowptr[idx] = run; head[idx] = run; run += cnt[idx]; }
  }
  if (t == 0) rowptr[O] = total;
}

// role-tagged incidence list: entry = (t<<1)|role, role 0 = subject, 1 = object
__global__ __launch_bounds__(256) void fill_k(const int* __restrict__ edges,
    int* __restrict__ head, int* __restrict__ list, int T) {
  int t = blockIdx.x * 256 + threadIdx.x;
  if (t < T) {
    int s = edges[2 * t];
    int p = atomicAdd(&head[s], 1);
    list[p] = t << 1;
    int o = edges[2 * t + 1];
    p = atomicAdd(&head[o], 1);
    list[p] = (t << 1) | 1;
  }
}

__global__ __launch_bounds__(256) void final_k(float* __restrict__ buf,
    const float* __restrict__ scale, const float* __restrict__ shift, int n) {
  int i = blockIdx.x * 256 + threadIdx.x;
  if (i < n) {
    int c = i & 127;
    float v = scale[c] * buf[i] + shift[c];
    buf[i] = v >= 0.f ? v : 0.2f * v;
  }
}

extern "C" void kernel_launch(void* const* d_in, const int* in_sizes, int n_in,
                              void* d_out, int out_size, void* d_ws, size_t ws_size,
                              hipStream_t stream) {
  const float* obj   = (const float*)d_in[0];
  const float* pred  = (const float*)d_in[1];
  const int*   edges = (const int*)d_in[2];
  const float* W1a = (const float*)d_in[3];
  const float* g1a = (const float*)d_in[5];
  const float* be1a= (const float*)d_in[6];
  const float* W1b = (const float*)d_in[7];
  const float* g1b = (const float*)d_in[9];
  const float* be1b= (const float*)d_in[10];
  const float* W2a = (const float*)d_in[11];
  const float* g2a = (const float*)d_in[13];
  const float* be2a= (const float*)d_in[14];
  const float* W2b = (const float*)d_in[15];
  const float* g2b = (const float*)d_in[17];
  const float* be2b= (const float*)d_in[18];

  const int O = in_sizes[0] / 128;
  const int T = in_sizes[1] / 128;
  float* out_obj = (float*)d_out;
  float* out_p   = (float*)d_out + (size_t)O * 128;

  char* base = (char*)d_ws;
  size_t off = 0;
  auto alloc = [&](size_t bytes) { size_t p = off; off += (bytes + 255) & ~(size_t)255; return p; };
  size_t oWT1a = alloc((size_t)384 * 512 * 2);
  size_t oWT1b = alloc((size_t)512 * 1152 * 2);
  size_t oWT2a = alloc((size_t)512 * 512 * 2);
  size_t oWT2b = alloc((size_t)512 * 128 * 2);
  size_t oSums = alloc(4608 * 4);
  size_t oScl  = alloc(4608 * 4);
  size_t oG    = alloc((size_t)512 * 512 * 4);
  size_t oCsum = alloc(512 * 4);
  size_t oCnt  = alloc((size_t)O * 4);
  size_t oInvc = alloc((size_t)O * 4);
  size_t oRp   = alloc((size_t)(O + 1) * 4);
  size_t oHead = alloc((size_t)O * 4);
  size_t oList = alloc((size_t)2 * T * 4);
  size_t oHA   = alloc((size_t)T * 512 * 2);    // hA/A2 bf16; h2 aliases later
  size_t oPool = off;                           // pooledF f32 (O,512)
  size_t oBuf  = oPool + (((size_t)O * 512 * 4 + 255) & ~(size_t)255);

  // chunk buffer: rows of 1024 bf16 ([s 512 | o 512])
  int chunkT = 0;
  if (ws_size > oBuf) {
    size_t ct = (ws_size - oBuf) / 2048;
    if (ct > (size_t)T) ct = T;
    chunkT = (int)(ct & ~(size_t)127);
  }
  const bool chunked = (chunkT >= 8192);

  bf16* WT1a = (bf16*)(base + oWT1a);
  bf16* WT1b = (bf16*)(base + oWT1b);
  bf16* WT2a = (bf16*)(base + oWT2a);
  bf16* WT2b = (bf16*)(base + oWT2b);
  float* sums = (float*)(base + oSums);
  float* sumA = sums,        * sqA = sums + 512;
  float* sumB = sums + 1024, * sqB = sums + 2176;
  float* sumC = sums + 3328, * sqC = sums + 3840;
  float* sumD = sums + 4352, * sqD = sums + 4480;
  float* scl = (float*)(base + oScl);
  float* scaleA = scl,        * shiftA = scl + 512;
  float* scaleB = scl + 1024, * shiftB = scl + 2176;
  float* scaleC = scl + 3328, * shiftC = scl + 3840;
  float* scaleD = scl + 4352, * shiftD = scl + 4480;
  float* Gm   = (float*)(base + oG);
  float* csum = (float*)(base + oCsum);
  int*   cntI = (int*)(base + oCnt);
  float* invc = (float*)(base + oInvc);
  int*   rowptr = (int*)(base + oRp);
  int*   head = (int*)(base + oHead);
  int*   list = (int*)(base + oList);
  bf16*  hA = (bf16*)(base + oHA);     // also A2 (in-place), later h2
  bf16*  h2 = (bf16*)(base + oHA);
  float* pooledF = (float*)(base + oPool);
  bf16*  buf = (bf16*)(base + oBuf);
  float* objpre = out_obj;

  hipMemsetAsync(sums, 0, 4608 * 4, stream);
  hipMemsetAsync(cntI, 0, (size_t)O * 4, stream);
  hipMemsetAsync(Gm, 0, (size_t)512 * 512 * 4, stream);
  hipMemsetAsync(csum, 0, 512 * 4, stream);
  hipMemsetAsync(pooledF, 0, (size_t)O * 512 * 4, stream);

  tconv_k<<<(384 * 512 + 255) / 256, 256, 0, stream>>>(W1a, WT1a, 384, 512);
  tconv_k<<<(512 * 1152 + 255) / 256, 256, 0, stream>>>(W1b, WT1b, 512, 1152);
  tconv_k<<<(512 * 512 + 255) / 256, 256, 0, stream>>>(W2a, WT2a, 512, 512);
  tconv_k<<<(512 * 128 + 255) / 256, 256, 0, stream>>>(W2b, WT2b, 512, 128);
  cntint_k<<<(T + 255) / 256, 256, 0, stream>>>(edges, cntI, T);
  invcnt_k<<<(O + 255) / 256, 256, 0, stream>>>(cntI, invc, O);
  if (chunked) {
    scan_k<<<1, 1024, 0, stream>>>(cntI, rowptr, head, O, 2 * T);
    fill_k<<<(T + 255) / 256, 256, 0, stream>>>(edges, head, list, T);
  }

  const int Tb = (T + BM - 1) / BM;
  const int Ob = (O + BM - 1) / BM;

  // GEMM1: gathered (T,384) @ W1a -> hA raw bf16 + statsA
  {
    dim3 g(512 / BN, Tb);
    gemm_k<0, 0><<<g, 256, 0, stream>>>(nullptr, nullptr, obj, pred, edges, nullptr,
        nullptr, nullptr, nullptr, nullptr, WT1a, hA, nullptr, nullptr, sumA, sqA,
        T, 512, 384, 0);
  }
  bnfin_k<<<2, 256, 0, stream>>>(sumA, sqA, g1a, be1a, scaleA, shiftA, 512, 1.f / T);

  // A2 = bn_lrelu(hA) in-place + column sums
  act_colsum_k<<<1024, 256, 0, stream>>>(hA, scaleA, shiftA, csum, T);
  // G = A2^T A2; then GEMM2 output stats algebraically
  gram_k<<<10 * 48, 256, 0, stream>>>(hA, Gm, T);
  colstat_k<<<288, 256, 0, stream>>>(Gm, csum, W1b, sumB, sqB);
  bnfin_k<<<5, 256, 0, stream>>>(sumB, sqB, g1b, be1b, scaleB, shiftB, 1152, 1.f / T);

  if (chunked) {
    // natural-order chunked GEMM2 with fused bn_lrelu; dense buf; CSR pooling
    for (int c0 = 0; c0 < T; c0 += chunkT) {
      int c1 = min(T, c0 + chunkT);
      dim3 g(1152 / BN, (c1 - c0 + BM - 1) / BM);
      gemm_k<3, 5><<<g, 256, 0, stream>>>(hA, nullptr, nullptr, nullptr, nullptr,
          nullptr, nullptr, nullptr, scaleB, shiftB, WT1b, buf, out_p, nullptr,
          nullptr, nullptr, c1, 1152, 512, c0);
      gatherc_k<<<(O + 3) / 4, 256, 0, stream>>>(buf, rowptr, list, pooledF, c0, c1, O);
    }
  } else {
    // tier-3: single GEMM2 pass with atomic scatter
    dim3 g(1152 / BN, Tb);
    gemm_k<3, 2><<<g, 256, 0, stream>>>(hA, nullptr, nullptr, nullptr, edges, nullptr,
        nullptr, nullptr, scaleB, shiftB, WT1b, nullptr, out_p, pooledF, nullptr,
        nullptr, T, 1152, 512, 0);
  }

  // GEMM3: (pooledF * invc) (O,512) @ W2a -> h2 bf16 + statsC
  {
    dim3 g(512 / BN, Ob);
    gemm_k<2, 0><<<g, 256, 0, stream>>>(nullptr, pooledF, nullptr, nullptr, nullptr,
        invc, nullptr, nullptr, nullptr, nullptr, WT2a, h2, nullptr, nullptr,
        sumC, sqC, O, 512, 512, 0);
  }
  bnfin_k<<<2, 256, 0, stream>>>(sumC, sqC, g2a, be2a, scaleC, shiftC, 512, 1.f / O);

  // GEMM4: bn_lrelu(h2) (O,512) @ W2b -> objpre f32 (in d_out) + statsD
  {
    dim3 g(128 / BN, Ob);
    gemm_k<1, 3><<<g, 256, 0, stream>>>(h2, nullptr, nullptr, nullptr, nullptr, nullptr,
        scaleC, shiftC, nullptr, nullptr, WT2b, nullptr, objpre, nullptr, sumD, sqD,
        O, 128, 512, 0);
  }
  bnfin_k<<<1, 256, 0, stream>>>(sumD, sqD, g2b, be2b, scaleD, shiftD, 128, 1.f / O);

  final_k<<<((size_t)O * 128 + 255) / 256, 256, 0, stream>>>(objpre, scaleD, shiftD,
      (int)((size_t)O * 128));
}